// Round 1
// baseline (24126.019 us; speedup 1.0000x reference)
//
#include <hip/hip_runtime.h>
#include <hip/hip_bf16.h>

// Problem dims (B=1)
constexpr int S_   = 2048;
constexpr int D_   = 2048;
constexpr int H_   = 16;
constexpr int DH_  = 128;
constexpr int L_   = 2;
constexpr int DFF_ = 8192;
constexpr int V_   = 32000;
constexpr int R_   = 8;

__constant__ float c_nf4[16] = {
  -1.0f, -0.6961928009986877f, -0.5250730514526367f, -0.39491748809814453f,
  -0.28444138169288635f, -0.18477343022823334f, -0.09105003625154495f, 0.0f,
  0.07958029955625534f, 0.16093020141124725f, 0.24611230194568634f,
  0.33791524171829224f, 0.44070982933044434f, 0.5626170039176941f,
  0.7229568362236023f, 1.0f };

// ---------------- embedding gather ----------------
__global__ __launch_bounds__(256) void k_gather(const int* __restrict__ ids,
                                                const float* __restrict__ emb,
                                                float* __restrict__ h) {
  int t = blockIdx.x * 256 + threadIdx.x;   // S*D threads
  int s = t >> 11;          // / D_
  int d = t & 2047;
  h[t] = emb[(size_t)ids[s] * D_ + d];
}

// ---------------- rmsnorm (block per row) ----------------
__global__ __launch_bounds__(256) void k_rmsnorm(const float* __restrict__ in,
                                                 const float* __restrict__ w,
                                                 float* __restrict__ out) {
  int s = blockIdx.x;
  const float* x = in + (size_t)s * D_;
  float ss = 0.f;
  for (int d = threadIdx.x; d < D_; d += 256) { float v = x[d]; ss += v * v; }
#pragma unroll
  for (int m = 1; m < 64; m <<= 1) ss += __shfl_xor(ss, m, 64);
  __shared__ float sh[4];
  if ((threadIdx.x & 63) == 0) sh[threadIdx.x >> 6] = ss;
  __syncthreads();
  ss = sh[0] + sh[1] + sh[2] + sh[3];
  float sc = rsqrtf(ss * (1.0f / D_) + 1e-6f);
  float* o = out + (size_t)s * D_;
  for (int d = threadIdx.x; d < D_; d += 256) o[d] = x[d] * sc * w[d];
}

// ---------------- GEMM: C[M,N] (=|+=) A[M,K] * B^T (B [N,K]) or A*B (B [K,N]) ----
// DEQ: B comes from nf4 idx+scale.  BT: B is [N,K] row-major (K contiguous).
template<bool DEQ, bool BT, bool BETA1>
__global__ __launch_bounds__(256) void k_gemm(const float* __restrict__ A, int lda,
                                              const float* __restrict__ Bf,
                                              const int* __restrict__ Bi,
                                              const float* __restrict__ Bs,
                                              float* __restrict__ C, int ldc,
                                              int N, int K) {
  __shared__ float As[16][68];
  __shared__ float Bsh[16][68];
  int tid = threadIdx.x;
  int n0 = blockIdx.x * 64, m0 = blockIdx.y * 64;
  int tx = tid & 15, ty = tid >> 4;
  float acc[4][4] = {{0.f}};
  for (int kt = 0; kt < K; kt += 16) {
    {
      int r = tid >> 2, kq = (tid & 3) << 2;
      const float4 av = *(const float4*)(A + (size_t)(m0 + r) * lda + kt + kq);
      As[kq + 0][r] = av.x; As[kq + 1][r] = av.y;
      As[kq + 2][r] = av.z; As[kq + 3][r] = av.w;
    }
    if (BT) {
      int r = tid >> 2, kq = (tid & 3) << 2;
      if (DEQ) {
        const int4 iv = *(const int4*)(Bi + (size_t)(n0 + r) * K + kt + kq);
        float scl = Bs[(size_t)(n0 + r) * (K >> 6) + ((kt + kq) >> 6)];
        Bsh[kq + 0][r] = c_nf4[iv.x] * scl;
        Bsh[kq + 1][r] = c_nf4[iv.y] * scl;
        Bsh[kq + 2][r] = c_nf4[iv.z] * scl;
        Bsh[kq + 3][r] = c_nf4[iv.w] * scl;
      } else {
        const float4 bv = *(const float4*)(Bf + (size_t)(n0 + r) * K + kt + kq);
        Bsh[kq + 0][r] = bv.x; Bsh[kq + 1][r] = bv.y;
        Bsh[kq + 2][r] = bv.z; Bsh[kq + 3][r] = bv.w;
      }
    } else {
      int kk = tid >> 4, n4 = (tid & 15) << 2;
      const float4 bv = *(const float4*)(Bf + (size_t)(kt + kk) * N + n0 + n4);
      *(float4*)&Bsh[kk][n4] = bv;
    }
    __syncthreads();
#pragma unroll
    for (int k = 0; k < 16; ++k) {
      float4 a = *(const float4*)&As[k][ty << 2];
      float4 b = *(const float4*)&Bsh[k][tx << 2];
      acc[0][0] += a.x * b.x; acc[0][1] += a.x * b.y; acc[0][2] += a.x * b.z; acc[0][3] += a.x * b.w;
      acc[1][0] += a.y * b.x; acc[1][1] += a.y * b.y; acc[1][2] += a.y * b.z; acc[1][3] += a.y * b.w;
      acc[2][0] += a.z * b.x; acc[2][1] += a.z * b.y; acc[2][2] += a.z * b.z; acc[2][3] += a.z * b.w;
      acc[3][0] += a.w * b.x; acc[3][1] += a.w * b.y; acc[3][2] += a.w * b.z; acc[3][3] += a.w * b.w;
    }
    __syncthreads();
  }
#pragma unroll
  for (int i = 0; i < 4; i++) {
    float* cp = C + (size_t)(m0 + (ty << 2) + i) * ldc + n0 + (tx << 2);
    float4 r = make_float4(acc[i][0], acc[i][1], acc[i][2], acc[i][3]);
    if (BETA1) { float4 o = *(const float4*)cp; r.x += o.x; r.y += o.y; r.z += o.z; r.w += o.w; }
    *(float4*)cp = r;
  }
}

// ---------------- LoRA down: T[s, i*R+r] = x_row . A[i][r] ----------------
__global__ __launch_bounds__(256) void k_lora_down(const float* __restrict__ X,
                                                   const float* __restrict__ A,
                                                   float* __restrict__ T, int nproj) {
  int s = blockIdx.x;
  int lane = threadIdx.x & 63, wv = threadIdx.x >> 6;
  const float* x = X + (size_t)s * D_;
  for (int p = wv; p < nproj * R_; p += 4) {
    const float* a = A + (size_t)p * D_;
    float sum = 0.f;
    for (int d = lane; d < D_; d += 64) sum += x[d] * a[d];
#pragma unroll
    for (int m = 1; m < 64; m <<= 1) sum += __shfl_xor(sum, m, 64);
    if (lane == 0) T[(size_t)s * (nproj * R_) + p] = sum;
  }
}

// ---------------- LoRA up: Y[s, i*D+d] += 2 * T[s,i,:] . B[i][d,:] ----------------
__global__ __launch_bounds__(256) void k_lora_up(float* __restrict__ Y, int ystride,
                                                 const float* __restrict__ T,
                                                 const float* __restrict__ Bm, int nproj) {
  int t = blockIdx.x * 256 + threadIdx.x;  // S*nproj*D threads
  int d = t & (D_ - 1);
  int si = t >> 11;
  int i = si % nproj;
  int s = si / nproj;
  const float* tp = T + ((size_t)s * nproj + i) * R_;
  const float* bp = Bm + ((size_t)i * D_ + d) * R_;
  float acc = 0.f;
#pragma unroll
  for (int r = 0; r < R_; r++) acc += tp[r] * bp[r];
  Y[(size_t)s * ystride + (size_t)i * D_ + d] += 2.0f * acc;  // alpha/r = 16/8
}

// ---------------- flash attention: 1 wave per (head,row) ----------------
__global__ __launch_bounds__(256) void k_attn(const float* __restrict__ qkv,
                                              float* __restrict__ out) {
  int lane = threadIdx.x & 63;
  int s = blockIdx.x * 4 + (threadIdx.x >> 6);
  int hh = blockIdx.y;
  const int ld = 3 * D_;
  const float rs = 0.08838834764831845f;  // 1/sqrt(128)
  const float* qp = qkv + (size_t)s * ld + hh * DH_;
  float q0 = qp[lane] * rs, q1 = qp[lane + 64] * rs;
  const float* kb = qkv + D_ + hh * DH_;
  const float* vb = qkv + 2 * D_ + hh * DH_;
  float m = -3.0e38f, l = 0.f, o0 = 0.f, o1 = 0.f;
  for (int kk = 0; kk <= s; ++kk) {
    const float* kp = kb + (size_t)kk * ld;
    float sc = q0 * kp[lane] + q1 * kp[lane + 64];
#pragma unroll
    for (int msk = 1; msk < 64; msk <<= 1) sc += __shfl_xor(sc, msk, 64);
    const float* vp = vb + (size_t)kk * ld;
    float mn = fmaxf(m, sc);
    float corr = __expf(m - mn);
    float p = __expf(sc - mn);
    l = l * corr + p;
    o0 = o0 * corr + p * vp[lane];
    o1 = o1 * corr + p * vp[lane + 64];
    m = mn;
  }
  float inv = 1.f / l;
  float* op = out + (size_t)s * D_ + hh * DH_;
  op[lane] = o0 * inv;
  op[lane + 64] = o1 * inv;
}

// ---------------- silu(gate)*up ----------------
__global__ __launch_bounds__(256) void k_silumul(const float* __restrict__ gu,
                                                 float* __restrict__ t) {
  int i = blockIdx.x * 256 + threadIdx.x;  // S*DFF threads
  int s = i >> 13;    // / DFF_
  int f = i & 8191;
  float g = gu[(size_t)s * (2 * DFF_) + f];
  float u = gu[(size_t)s * (2 * DFF_) + DFF_ + f];
  float sg = 1.f / (1.f + __expf(-g));
  t[i] = g * sg * u;
}

// ---------------- gumbel softmax -> g (block per row) ----------------
__global__ __launch_bounds__(256) void k_gumbel(const float* __restrict__ logits,
                                                const float* __restrict__ u,
                                                float* __restrict__ g) {
  int s = blockIdx.x;
  const float* lp = logits + (size_t)s * V_;
  const float* up = u + (size_t)s * V_;
  float m = -3.0e38f, l = 0.f;
  for (int v = threadIdx.x; v < V_; v += 256) {
    float z = lp[v] - __logf(-__logf(up[v] + 1e-10f) + 1e-10f);
    float mn = fmaxf(m, z);
    l = l * __expf(m - mn) + __expf(z - mn);
    m = mn;
  }
#pragma unroll
  for (int msk = 1; msk < 64; msk <<= 1) {
    float m2 = __shfl_xor(m, msk, 64), l2 = __shfl_xor(l, msk, 64);
    float mn = fmaxf(m, m2);
    l = l * __expf(m - mn) + l2 * __expf(m2 - mn);
    m = mn;
  }
  __shared__ float shm[4], shl[4];
  if ((threadIdx.x & 63) == 0) { shm[threadIdx.x >> 6] = m; shl[threadIdx.x >> 6] = l; }
  __syncthreads();
  float M = fmaxf(fmaxf(shm[0], shm[1]), fmaxf(shm[2], shm[3]));
  float L = shl[0] * __expf(shm[0] - M) + shl[1] * __expf(shm[1] - M) +
            shl[2] * __expf(shm[2] - M) + shl[3] * __expf(shm[3] - M);
  float inv = 1.f / L;
  float* gp = g + (size_t)s * V_;
  for (int v = threadIdx.x; v < V_; v += 256) {
    float z = lp[v] - __logf(-__logf(up[v] + 1e-10f) + 1e-10f);
    gp[v] = __expf(z - M) * inv;
  }
}

extern "C" void kernel_launch(void* const* d_in, const int* in_sizes, int n_in,
                              void* d_out, int out_size, void* d_ws, size_t ws_size,
                              hipStream_t stream) {
  const int*   ids        = (const int*)d_in[0];
  const float* u          = (const float*)d_in[1];
  const float* emb        = (const float*)d_in[2];
  const float* attn_scale = (const float*)d_in[3];
  const float* gu_scale   = (const float*)d_in[4];
  const float* dn_scale   = (const float*)d_in[5];
  const float* lora_A     = (const float*)d_in[6];
  const float* lora_B     = (const float*)d_in[7];
  const float* norm_w     = (const float*)d_in[8];
  const float* fnorm_w    = (const float*)d_in[9];
  const int*   attn_idx   = (const int*)d_in[10];
  const int*   gu_idx     = (const int*)d_in[11];
  const int*   dn_idx     = (const int*)d_in[12];

  float* out_se = (float*)d_out;                       // soft_embeddings [S,D]
  float* out_lg = (float*)d_out + (size_t)S_ * D_;     // logits [S,V]

  // workspace layout (floats). Peak = 64M floats = 256 MiB (g overlaps dead buffers)
  float* ws  = (float*)d_ws;
  float* h   = ws;                                     // [0,4M)
  float* x   = ws + (size_t)4 * 1024 * 1024;           // [4M,8M)
  float* qkv = ws + (size_t)8 * 1024 * 1024;           // [8M,20M)
  float* o   = ws + (size_t)20 * 1024 * 1024;          // [20M,24M)
  float* gu  = ws + (size_t)8 * 1024 * 1024;           // [8M,40M)  (after qkv/o dead)
  float* tb  = ws + (size_t)40 * 1024 * 1024;          // [40M,56M)
  float* Tl  = ws + (size_t)56 * 1024 * 1024;          // lora tmp (tiny)
  float* g   = ws;                                     // [0,64M) (after all layer scratch dead)

  dim3 b256(256);

  k_gather<<<dim3(S_ * D_ / 256), b256, 0, stream>>>(ids, emb, h);

  for (int l = 0; l < L_; ++l) {
    const int*   aidx = attn_idx + (size_t)l * 4 * D_ * D_;
    const float* ascl = attn_scale + (size_t)l * 4 * D_ * (D_ / 64);
    const float* lA   = lora_A + (size_t)l * 4 * R_ * D_;
    const float* lB   = lora_B + (size_t)l * 4 * D_ * R_;

    // ---- attention ----
    k_rmsnorm<<<dim3(S_), b256, 0, stream>>>(h, norm_w + (size_t)l * 2 * D_, x);
    k_gemm<true, true, false><<<dim3(3 * D_ / 64, S_ / 64), b256, 0, stream>>>(
        x, D_, nullptr, aidx, ascl, qkv, 3 * D_, 3 * D_, D_);
    k_lora_down<<<dim3(S_), b256, 0, stream>>>(x, lA, Tl, 3);
    k_lora_up<<<dim3(S_ * 3 * D_ / 256), b256, 0, stream>>>(qkv, 3 * D_, Tl, lB, 3);
    k_attn<<<dim3(S_ / 4, H_), b256, 0, stream>>>(qkv, o);
    k_gemm<true, true, true><<<dim3(D_ / 64, S_ / 64), b256, 0, stream>>>(
        o, D_, nullptr, aidx + (size_t)3 * D_ * D_, ascl + (size_t)3 * D_ * (D_ / 64),
        h, D_, D_, D_);
    k_lora_down<<<dim3(S_), b256, 0, stream>>>(o, lA + (size_t)3 * R_ * D_, Tl, 1);
    k_lora_up<<<dim3(S_ * D_ / 256), b256, 0, stream>>>(h, D_, Tl, lB + (size_t)3 * D_ * R_, 1);

    // ---- ffn ----
    k_rmsnorm<<<dim3(S_), b256, 0, stream>>>(h, norm_w + (size_t)l * 2 * D_ + D_, x);
    k_gemm<true, true, false><<<dim3(2 * DFF_ / 64, S_ / 64), b256, 0, stream>>>(
        x, D_, nullptr, gu_idx + (size_t)l * 2 * DFF_ * D_,
        gu_scale + (size_t)l * 2 * DFF_ * (D_ / 64), gu, 2 * DFF_, 2 * DFF_, D_);
    k_silumul<<<dim3(S_ * DFF_ / 256), b256, 0, stream>>>(gu, tb);
    k_gemm<true, true, true><<<dim3(D_ / 64, S_ / 64), b256, 0, stream>>>(
        tb, DFF_, nullptr, dn_idx + (size_t)l * D_ * DFF_,
        dn_scale + (size_t)l * D_ * (DFF_ / 64), h, D_, D_, DFF_);
  }

  // ---- head ----
  k_rmsnorm<<<dim3(S_), b256, 0, stream>>>(h, fnorm_w, x);
  k_gemm<false, true, false><<<dim3(V_ / 64, S_ / 64), b256, 0, stream>>>(
      x, D_, emb, nullptr, nullptr, out_lg, V_, V_, D_);
  k_gumbel<<<dim3(S_), b256, 0, stream>>>(out_lg, u, g);
  k_gemm<false, false, false><<<dim3(D_ / 64, S_ / 64), b256, 0, stream>>>(
      g, V_, emb, nullptr, nullptr, out_se, D_, D_, V_);
}

// Round 2
// 8494.355 us; speedup vs baseline: 2.8402x; 2.8402x over previous
//
#include <hip/hip_runtime.h>
#include <hip/hip_bf16.h>

typedef unsigned short u16;
typedef unsigned int u32;
typedef __bf16 bf16t;
typedef bf16t bf16x8 __attribute__((ext_vector_type(8)));
typedef float f32x4 __attribute__((ext_vector_type(4)));

constexpr int S_   = 2048;
constexpr int D_   = 2048;
constexpr int H_   = 16;
constexpr int DH_  = 128;
constexpr int L_   = 2;
constexpr int DFF_ = 8192;
constexpr int V_   = 32000;
constexpr int R_   = 8;

__constant__ float c_nf4[16] = {
  -1.0f, -0.6961928009986877f, -0.5250730514526367f, -0.39491748809814453f,
  -0.28444138169288635f, -0.18477343022823334f, -0.09105003625154495f, 0.0f,
  0.07958029955625534f, 0.16093020141124725f, 0.24611230194568634f,
  0.33791524171829224f, 0.44070982933044434f, 0.5626170039176941f,
  0.7229568362236023f, 1.0f };

__device__ __forceinline__ u16 f2bf(float f) {
  union { float f; u32 u; } v; v.f = f;
  u32 r = v.u + 0x7fffu + ((v.u >> 16) & 1u);
  return (u16)(r >> 16);
}
__device__ __forceinline__ float bf2f(u16 h) {
  union { u32 u; float f; } v; v.u = ((u32)h) << 16; return v.f;
}

// ---------------- embedding gather ----------------
__global__ __launch_bounds__(256) void k_gather(const int* __restrict__ ids,
                                                const float* __restrict__ emb,
                                                float* __restrict__ h) {
  int t = blockIdx.x * 256 + threadIdx.x;
  int s = t >> 11;
  int d = t & 2047;
  h[t] = emb[(size_t)ids[s] * D_ + d];
}

// ---------------- rmsnorm f32 -> bf16 ----------------
__global__ __launch_bounds__(256) void k_rmsnorm(const float* __restrict__ in,
                                                 const float* __restrict__ w,
                                                 u16* __restrict__ out) {
  int s = blockIdx.x;
  const float* x = in + (size_t)s * D_;
  float ss = 0.f;
  for (int d = threadIdx.x; d < D_; d += 256) { float v = x[d]; ss += v * v; }
#pragma unroll
  for (int m = 1; m < 64; m <<= 1) ss += __shfl_xor(ss, m, 64);
  __shared__ float sh[4];
  if ((threadIdx.x & 63) == 0) sh[threadIdx.x >> 6] = ss;
  __syncthreads();
  ss = sh[0] + sh[1] + sh[2] + sh[3];
  float sc = rsqrtf(ss * (1.0f / D_) + 1e-6f);
  u16* o = out + (size_t)s * D_;
  for (int d = threadIdx.x; d < D_; d += 256) o[d] = f2bf(x[d] * sc * w[d]);
}

// ---------------- NF4 dequant: idx int32 [N,K] + scale [N,K/64] -> bf16 [N,K] ----
__global__ __launch_bounds__(256) void k_dequant(const int* __restrict__ idx,
                                                 const float* __restrict__ scale,
                                                 u16* __restrict__ out, int kshift) {
  size_t t = (size_t)blockIdx.x * 256 + threadIdx.x;
  size_t e = t * 8;
  int k = (int)(e & ((1u << kshift) - 1));
  size_t n = e >> kshift;
  float s = scale[(n << (kshift - 6)) + (k >> 6)];
  int4 i0 = *(const int4*)(idx + e);
  int4 i1 = *(const int4*)(idx + e + 4);
  uint4 o;
  o.x = (u32)f2bf(c_nf4[i0.x] * s) | ((u32)f2bf(c_nf4[i0.y] * s) << 16);
  o.y = (u32)f2bf(c_nf4[i0.z] * s) | ((u32)f2bf(c_nf4[i0.w] * s) << 16);
  o.z = (u32)f2bf(c_nf4[i1.x] * s) | ((u32)f2bf(c_nf4[i1.y] * s) << 16);
  o.w = (u32)f2bf(c_nf4[i1.z] * s) | ((u32)f2bf(c_nf4[i1.w] * s) << 16);
  *(uint4*)(out + e) = o;
}

// ---------------- f32 -> bf16 convert (emb) ----------------
__global__ __launch_bounds__(256) void k_f2b(const float* __restrict__ src,
                                             u16* __restrict__ dst) {
  size_t e = ((size_t)blockIdx.x * 256 + threadIdx.x) * 8;
  float4 f0 = *(const float4*)(src + e);
  float4 f1 = *(const float4*)(src + e + 4);
  uint4 o;
  o.x = (u32)f2bf(f0.x) | ((u32)f2bf(f0.y) << 16);
  o.y = (u32)f2bf(f0.z) | ((u32)f2bf(f0.w) << 16);
  o.z = (u32)f2bf(f1.x) | ((u32)f2bf(f1.y) << 16);
  o.w = (u32)f2bf(f1.z) | ((u32)f2bf(f1.w) << 16);
  *(uint4*)(dst + e) = o;
}

// ---------------- transpose-convert: emb f32 [V,D] -> embT bf16 [D,V] ----------
__global__ __launch_bounds__(256) void k_transpose(const float* __restrict__ src,
                                                   u16* __restrict__ dst) {
  __shared__ u16 tile[64][65];
  int v0 = blockIdx.x * 64, d0 = blockIdx.y * 64;
  int tid = threadIdx.x;
  int rr = tid >> 4, cc = (tid & 15) * 4;
#pragma unroll
  for (int j = 0; j < 4; ++j) {
    int r = j * 16 + rr;
    float4 f = *(const float4*)(src + (size_t)(v0 + r) * D_ + d0 + cc);
    tile[r][cc + 0] = f2bf(f.x); tile[r][cc + 1] = f2bf(f.y);
    tile[r][cc + 2] = f2bf(f.z); tile[r][cc + 3] = f2bf(f.w);
  }
  __syncthreads();
#pragma unroll
  for (int j = 0; j < 4; ++j) {
    int r = j * 16 + rr;          // d-local
    ushort4 w;
    w.x = tile[cc + 0][r]; w.y = tile[cc + 1][r];
    w.z = tile[cc + 2][r]; w.w = tile[cc + 3][r];
    *(ushort4*)(dst + (size_t)(d0 + r) * V_ + v0 + cc) = w;
  }
}

// ---------------- MFMA GEMM: C[M,N] = A[M,K](lda) * B[N,K]^T, bf16 in, 128x128 tile ----
enum { OUT_F32 = 0, OUT_F32_ACC = 1, OUT_BF16 = 2 };

template<int OUTMODE>
__global__ __launch_bounds__(256) void k_mfma_gemm(const u16* __restrict__ A, int lda,
                                                   const u16* __restrict__ B,
                                                   void* __restrict__ Cv, int ldc, int K) {
  __shared__ u16 As[128 * 64];
  __shared__ u16 Bs[128 * 64];
  const int tid = threadIdx.x;
  const int lane = tid & 63, w = tid >> 6;
  const int wm = w >> 1, wn = w & 1;
  const int m0 = blockIdx.y * 128, n0 = blockIdx.x * 128;

  f32x4 acc[4][4] = {};

  const int srow = w * 32 + (lane >> 3);   // staged row (issue 0)
  const int scol = (lane & 7) * 8;         // k offset within BK=64
  const size_t a_base = (size_t)(m0 + srow) * lda + scol;
  const size_t b_base = (size_t)(n0 + srow) * (size_t)K + scol;

  for (int kt = 0; kt < K; kt += 64) {
    __syncthreads();   // previous iter's LDS reads done
#pragma unroll
    for (int i = 0; i < 4; ++i) {
      __builtin_amdgcn_global_load_lds(
          (const __attribute__((address_space(1))) void*)(A + a_base + (size_t)(i * 8) * lda + kt),
          (__attribute__((address_space(3))) void*)(&As[(w * 32 + i * 8) * 64]), 16, 0, 0);
      __builtin_amdgcn_global_load_lds(
          (const __attribute__((address_space(1))) void*)(B + b_base + (size_t)(i * 8) * K + kt),
          (__attribute__((address_space(3))) void*)(&Bs[(w * 32 + i * 8) * 64]), 16, 0, 0);
    }
    __syncthreads();   // staged (vmcnt(0) drained by barrier)
#pragma unroll
    for (int kh = 0; kh < 2; ++kh) {
      bf16x8 af[4], bfr[4];
#pragma unroll
      for (int m = 0; m < 4; ++m)
        af[m] = *(const bf16x8*)&As[(wm * 64 + m * 16 + (lane & 15)) * 64 + kh * 32 + (lane >> 4) * 8];
#pragma unroll
      for (int n = 0; n < 4; ++n)
        bfr[n] = *(const bf16x8*)&Bs[(wn * 64 + n * 16 + (lane & 15)) * 64 + kh * 32 + (lane >> 4) * 8];
#pragma unroll
      for (int m = 0; m < 4; ++m)
#pragma unroll
        for (int n = 0; n < 4; ++n)
          acc[m][n] = __builtin_amdgcn_mfma_f32_16x16x32_bf16(af[m], bfr[n], acc[m][n], 0, 0, 0);
    }
  }
  const int er = (lane >> 4) * 4;
  const int ec = lane & 15;
#pragma unroll
  for (int m = 0; m < 4; ++m)
#pragma unroll
    for (int n = 0; n < 4; ++n)
#pragma unroll
      for (int r = 0; r < 4; ++r) {
        int row = m0 + wm * 64 + m * 16 + er + r;
        int col = n0 + wn * 64 + n * 16 + ec;
        if (OUTMODE == OUT_BF16) {
          ((u16*)Cv)[(size_t)row * ldc + col] = f2bf(acc[m][n][r]);
        } else if (OUTMODE == OUT_F32_ACC) {
          ((float*)Cv)[(size_t)row * ldc + col] += acc[m][n][r];
        } else {
          ((float*)Cv)[(size_t)row * ldc + col] = acc[m][n][r];
        }
      }
}

// ---------------- LoRA down: T[s, p] = x_row(bf16) . A[p] ----------------
__global__ __launch_bounds__(256) void k_lora_down(const u16* __restrict__ X,
                                                   const float* __restrict__ A,
                                                   float* __restrict__ T, int nproj) {
  int s = blockIdx.x;
  int lane = threadIdx.x & 63, wv = threadIdx.x >> 6;
  const u16* x = X + (size_t)s * D_;
  for (int p = wv; p < nproj * R_; p += 4) {
    const float* a = A + (size_t)p * D_;
    float sum = 0.f;
    for (int d = lane; d < D_; d += 64) sum += bf2f(x[d]) * a[d];
#pragma unroll
    for (int m = 1; m < 64; m <<= 1) sum += __shfl_xor(sum, m, 64);
    if (lane == 0) T[(size_t)s * (nproj * R_) + p] = sum;
  }
}

// ---------------- LoRA up: Y[s, i*D+d] += 2 * T[s,i,:] . B[i][d,:] ----------------
__global__ __launch_bounds__(256) void k_lora_up(float* __restrict__ Y, int ystride,
                                                 const float* __restrict__ T,
                                                 const float* __restrict__ Bm, int nproj) {
  int t = blockIdx.x * 256 + threadIdx.x;
  int d = t & (D_ - 1);
  int si = t >> 11;
  int i = si % nproj;
  int s = si / nproj;
  const float* tp = T + ((size_t)s * nproj + i) * R_;
  const float* bp = Bm + ((size_t)i * D_ + d) * R_;
  float acc = 0.f;
#pragma unroll
  for (int r = 0; r < R_; r++) acc += tp[r] * bp[r];
  Y[(size_t)s * ystride + (size_t)i * D_ + d] += 2.0f * acc;
}

// ---------------- flash attention (f32 qkv), out bf16 ----------------
__global__ __launch_bounds__(256) void k_attn(const float* __restrict__ qkv,
                                              u16* __restrict__ out) {
  int lane = threadIdx.x & 63;
  int s = blockIdx.x * 4 + (threadIdx.x >> 6);
  int hh = blockIdx.y;
  const int ld = 3 * D_;
  const float rs = 0.08838834764831845f;
  const float* qp = qkv + (size_t)s * ld + hh * DH_;
  float q0 = qp[lane] * rs, q1 = qp[lane + 64] * rs;
  const float* kb = qkv + D_ + hh * DH_;
  const float* vb = qkv + 2 * D_ + hh * DH_;
  float m = -3.0e38f, l = 0.f, o0 = 0.f, o1 = 0.f;
  for (int kk = 0; kk <= s; ++kk) {
    const float* kp = kb + (size_t)kk * ld;
    float sc = q0 * kp[lane] + q1 * kp[lane + 64];
#pragma unroll
    for (int msk = 1; msk < 64; msk <<= 1) sc += __shfl_xor(sc, msk, 64);
    const float* vp = vb + (size_t)kk * ld;
    float mn = fmaxf(m, sc);
    float corr = __expf(m - mn);
    float p = __expf(sc - mn);
    l = l * corr + p;
    o0 = o0 * corr + p * vp[lane];
    o1 = o1 * corr + p * vp[lane + 64];
    m = mn;
  }
  float inv = 1.f / l;
  u16* op = out + (size_t)s * D_ + hh * DH_;
  op[lane] = f2bf(o0 * inv);
  op[lane + 64] = f2bf(o1 * inv);
}

// ---------------- silu(gate)*up, in-place into gate half (bf16) ----------------
__global__ __launch_bounds__(256) void k_silumul(u16* __restrict__ gu) {
  size_t i = ((size_t)blockIdx.x * 256 + threadIdx.x) * 4;
  int s = (int)(i >> 13);
  int f = (int)(i & 8191);
  u16* gp = gu + (size_t)s * (2 * DFF_) + f;
  ushort4 gt = *(ushort4*)gp;
  ushort4 up = *(ushort4*)(gp + DFF_);
  float g0 = bf2f(gt.x), g1 = bf2f(gt.y), g2 = bf2f(gt.z), g3 = bf2f(gt.w);
  float u0 = bf2f(up.x), u1 = bf2f(up.y), u2 = bf2f(up.z), u3 = bf2f(up.w);
  ushort4 o;
  o.x = f2bf(g0 / (1.f + __expf(-g0)) * u0);
  o.y = f2bf(g1 / (1.f + __expf(-g1)) * u1);
  o.z = f2bf(g2 / (1.f + __expf(-g2)) * u2);
  o.w = f2bf(g3 / (1.f + __expf(-g3)) * u3);
  *(ushort4*)gp = o;
}

// ---------------- gumbel softmax -> g (bf16) ----------------
__global__ __launch_bounds__(256) void k_gumbel(const float* __restrict__ logits,
                                                const float* __restrict__ u,
                                                u16* __restrict__ g) {
  int s = blockIdx.x;
  const float* lp = logits + (size_t)s * V_;
  const float* up = u + (size_t)s * V_;
  float m = -3.0e38f, l = 0.f;
  for (int v = threadIdx.x; v < V_; v += 256) {
    float z = lp[v] - __logf(-__logf(up[v] + 1e-10f) + 1e-10f);
    float mn = fmaxf(m, z);
    l = l * __expf(m - mn) + __expf(z - mn);
    m = mn;
  }
#pragma unroll
  for (int msk = 1; msk < 64; msk <<= 1) {
    float m2 = __shfl_xor(m, msk, 64), l2 = __shfl_xor(l, msk, 64);
    float mn = fmaxf(m, m2);
    l = l * __expf(m - mn) + l2 * __expf(m2 - mn);
    m = mn;
  }
  __shared__ float shm[4], shl[4];
  if ((threadIdx.x & 63) == 0) { shm[threadIdx.x >> 6] = m; shl[threadIdx.x >> 6] = l; }
  __syncthreads();
  float M = fmaxf(fmaxf(shm[0], shm[1]), fmaxf(shm[2], shm[3]));
  float L = shl[0] * __expf(shm[0] - M) + shl[1] * __expf(shm[1] - M) +
            shl[2] * __expf(shm[2] - M) + shl[3] * __expf(shm[3] - M);
  float inv = 1.f / L;
  u16* gp = g + (size_t)s * V_;
  for (int v = threadIdx.x; v < V_; v += 256) {
    float z = lp[v] - __logf(-__logf(up[v] + 1e-10f) + 1e-10f);
    gp[v] = f2bf(__expf(z - M) * inv);
  }
}

extern "C" void kernel_launch(void* const* d_in, const int* in_sizes, int n_in,
                              void* d_out, int out_size, void* d_ws, size_t ws_size,
                              hipStream_t stream) {
  const int*   ids        = (const int*)d_in[0];
  const float* u          = (const float*)d_in[1];
  const float* emb        = (const float*)d_in[2];
  const float* attn_scale = (const float*)d_in[3];
  const float* gu_scale   = (const float*)d_in[4];
  const float* dn_scale   = (const float*)d_in[5];
  const float* lora_A     = (const float*)d_in[6];
  const float* lora_B     = (const float*)d_in[7];
  const float* norm_w     = (const float*)d_in[8];
  const float* fnorm_w    = (const float*)d_in[9];
  const int*   attn_idx   = (const int*)d_in[10];
  const int*   gu_idx     = (const int*)d_in[11];
  const int*   dn_idx     = (const int*)d_in[12];

  float* out_se = (float*)d_out;
  float* out_lg = (float*)d_out + (size_t)S_ * D_;

  // workspace (byte offsets, MiB). Layer phase peak 208 MiB; head phase 250 MiB.
  char* W = (char*)d_ws;
  float* h    = (float*)(W);                          // 16 MiB
  u16*   xb   = (u16*)(W + ((size_t)16 << 20));       // 8 MiB
  float* qkv  = (float*)(W + ((size_t)24 << 20));     // 48 MiB
  u16*   ob   = (u16*)(W + ((size_t)72 << 20));       // 8 MiB
  u16*   gub  = (u16*)(W + ((size_t)80 << 20));       // 64 MiB
  u16*   wdq  = (u16*)(W + ((size_t)144 << 20));      // 64 MiB
  float* Tl   = (float*)(W + ((size_t)208 << 20));    // 192 KiB
  u16*   embb = (u16*)(W);                            // 125 MiB (head)
  u16*   gsm  = (u16*)(W + ((size_t)125 << 20));      // 125 MiB (head)
  u16*   embT = (u16*)(W);                            // 125 MiB (replaces embb)
  u16*   xbh  = (u16*)d_out;                          // final-norm out, parked in out_se

  dim3 b256(256);

  k_gather<<<dim3(S_ * D_ / 256), b256, 0, stream>>>(ids, emb, h);

  for (int l = 0; l < L_; ++l) {
    const int*   aidx = attn_idx + (size_t)l * 4 * D_ * D_;
    const float* ascl = attn_scale + (size_t)l * 4 * D_ * (D_ / 64);
    const float* lA   = lora_A + (size_t)l * 4 * R_ * D_;
    const float* lB   = lora_B + (size_t)l * 4 * D_ * R_;

    // ---- attention ----
    k_rmsnorm<<<dim3(S_), b256, 0, stream>>>(h, norm_w + (size_t)l * 2 * D_, xb);
    k_dequant<<<dim3(4 * D_ * D_ / 8 / 256), b256, 0, stream>>>(aidx, ascl, wdq, 11);
    k_mfma_gemm<OUT_F32><<<dim3(3 * D_ / 128, S_ / 128), b256, 0, stream>>>(
        xb, D_, wdq, qkv, 3 * D_, D_);
    k_lora_down<<<dim3(S_), b256, 0, stream>>>(xb, lA, Tl, 3);
    k_lora_up<<<dim3(S_ * 3 * D_ / 256), b256, 0, stream>>>(qkv, 3 * D_, Tl, lB, 3);
    k_attn<<<dim3(S_ / 4, H_), b256, 0, stream>>>(qkv, ob);
    k_mfma_gemm<OUT_F32_ACC><<<dim3(D_ / 128, S_ / 128), b256, 0, stream>>>(
        ob, D_, wdq + (size_t)3 * D_ * D_, h, D_, D_);
    k_lora_down<<<dim3(S_), b256, 0, stream>>>(ob, lA + (size_t)3 * R_ * D_, Tl, 1);
    k_lora_up<<<dim3(S_ * D_ / 256), b256, 0, stream>>>(h, D_, Tl, lB + (size_t)3 * D_ * R_, 1);

    // ---- ffn ----
    k_rmsnorm<<<dim3(S_), b256, 0, stream>>>(h, norm_w + (size_t)l * 2 * D_ + D_, xb);
    k_dequant<<<dim3(2 * DFF_ * D_ / 8 / 256), b256, 0, stream>>>(
        gu_idx + (size_t)l * 2 * DFF_ * D_, gu_scale + (size_t)l * 2 * DFF_ * (D_ / 64), wdq, 11);
    k_mfma_gemm<OUT_BF16><<<dim3(2 * DFF_ / 128, S_ / 128), b256, 0, stream>>>(
        xb, D_, wdq, gub, 2 * DFF_, D_);
    k_silumul<<<dim3(S_ * DFF_ / 4 / 256), b256, 0, stream>>>(gub);
    k_dequant<<<dim3(D_ * DFF_ / 8 / 256), b256, 0, stream>>>(
        dn_idx + (size_t)l * D_ * DFF_, dn_scale + (size_t)l * D_ * (DFF_ / 64), wdq, 13);
    k_mfma_gemm<OUT_F32_ACC><<<dim3(D_ / 128, S_ / 128), b256, 0, stream>>>(
        gub, 2 * DFF_, wdq, h, D_, DFF_);
  }

  // ---- head ----
  k_rmsnorm<<<dim3(S_), b256, 0, stream>>>(h, fnorm_w, xbh);
  k_f2b<<<dim3(V_ * D_ / 8 / 256), b256, 0, stream>>>(emb, embb);
  k_mfma_gemm<OUT_F32><<<dim3(V_ / 128, S_ / 128), b256, 0, stream>>>(
      xbh, D_, embb, out_lg, V_, D_);
  k_gumbel<<<dim3(S_), b256, 0, stream>>>(out_lg, u, gsm);
  k_transpose<<<dim3(V_ / 64, D_ / 64), b256, 0, stream>>>(emb, embT);
  k_mfma_gemm<OUT_F32><<<dim3(D_ / 128, S_ / 128), b256, 0, stream>>>(
      gsm, V_, embT, out_se, D_, V_);
}

// Round 3
// 3745.876 us; speedup vs baseline: 6.4407x; 2.2677x over previous
//
#include <hip/hip_runtime.h>
#include <hip/hip_bf16.h>

typedef unsigned short u16;
typedef unsigned int u32;
typedef __bf16 bf16t;
typedef bf16t bf16x8 __attribute__((ext_vector_type(8)));
typedef float f32x4 __attribute__((ext_vector_type(4)));

constexpr int S_   = 2048;
constexpr int D_   = 2048;
constexpr int H_   = 16;
constexpr int DH_  = 128;
constexpr int L_   = 2;
constexpr int DFF_ = 8192;
constexpr int V_   = 32000;
constexpr int R_   = 8;

__constant__ float c_nf4[16] = {
  -1.0f, -0.6961928009986877f, -0.5250730514526367f, -0.39491748809814453f,
  -0.28444138169288635f, -0.18477343022823334f, -0.09105003625154495f, 0.0f,
  0.07958029955625534f, 0.16093020141124725f, 0.24611230194568634f,
  0.33791524171829224f, 0.44070982933044434f, 0.5626170039176941f,
  0.7229568362236023f, 1.0f };

__device__ __forceinline__ u16 f2bf(float f) {
  union { float f; u32 u; } v; v.f = f;
  u32 r = v.u + 0x7fffu + ((v.u >> 16) & 1u);
  return (u16)(r >> 16);
}
__device__ __forceinline__ float bf2f(u16 h) {
  union { u32 u; float f; } v; v.u = ((u32)h) << 16; return v.f;
}

// ---------------- embedding gather ----------------
__global__ __launch_bounds__(256) void k_gather(const int* __restrict__ ids,
                                                const float* __restrict__ emb,
                                                float* __restrict__ h) {
  int t = blockIdx.x * 256 + threadIdx.x;
  int s = t >> 11;
  int d = t & 2047;
  h[t] = emb[(size_t)ids[s] * D_ + d];
}

// ---------------- rmsnorm f32 -> bf16 ----------------
__global__ __launch_bounds__(256) void k_rmsnorm(const float* __restrict__ in,
                                                 const float* __restrict__ w,
                                                 u16* __restrict__ out) {
  int s = blockIdx.x;
  const float* x = in + (size_t)s * D_;
  float ss = 0.f;
  for (int d = threadIdx.x; d < D_; d += 256) { float v = x[d]; ss += v * v; }
#pragma unroll
  for (int m = 1; m < 64; m <<= 1) ss += __shfl_xor(ss, m, 64);
  __shared__ float sh[4];
  if ((threadIdx.x & 63) == 0) sh[threadIdx.x >> 6] = ss;
  __syncthreads();
  ss = sh[0] + sh[1] + sh[2] + sh[3];
  float sc = rsqrtf(ss * (1.0f / D_) + 1e-6f);
  u16* o = out + (size_t)s * D_;
  for (int d = threadIdx.x; d < D_; d += 256) o[d] = f2bf(x[d] * sc * w[d]);
}

// ---------------- NF4 dequant ----------------
__global__ __launch_bounds__(256) void k_dequant(const int* __restrict__ idx,
                                                 const float* __restrict__ scale,
                                                 u16* __restrict__ out, int kshift) {
  size_t t = (size_t)blockIdx.x * 256 + threadIdx.x;
  size_t e = t * 8;
  int k = (int)(e & ((1u << kshift) - 1));
  size_t n = e >> kshift;
  float s = scale[(n << (kshift - 6)) + (k >> 6)];
  int4 i0 = *(const int4*)(idx + e);
  int4 i1 = *(const int4*)(idx + e + 4);
  uint4 o;
  o.x = (u32)f2bf(c_nf4[i0.x] * s) | ((u32)f2bf(c_nf4[i0.y] * s) << 16);
  o.y = (u32)f2bf(c_nf4[i0.z] * s) | ((u32)f2bf(c_nf4[i0.w] * s) << 16);
  o.z = (u32)f2bf(c_nf4[i1.x] * s) | ((u32)f2bf(c_nf4[i1.y] * s) << 16);
  o.w = (u32)f2bf(c_nf4[i1.z] * s) | ((u32)f2bf(c_nf4[i1.w] * s) << 16);
  *(uint4*)(out + e) = o;
}

// ---------------- f32 -> bf16 convert (emb) ----------------
__global__ __launch_bounds__(256) void k_f2b(const float* __restrict__ src,
                                             u16* __restrict__ dst) {
  size_t e = ((size_t)blockIdx.x * 256 + threadIdx.x) * 8;
  float4 f0 = *(const float4*)(src + e);
  float4 f1 = *(const float4*)(src + e + 4);
  uint4 o;
  o.x = (u32)f2bf(f0.x) | ((u32)f2bf(f0.y) << 16);
  o.y = (u32)f2bf(f0.z) | ((u32)f2bf(f0.w) << 16);
  o.z = (u32)f2bf(f1.x) | ((u32)f2bf(f1.y) << 16);
  o.w = (u32)f2bf(f1.z) | ((u32)f2bf(f1.w) << 16);
  *(uint4*)(dst + e) = o;
}

// ---------------- transpose-convert: emb f32 [V,D] -> embT bf16 [D,V] ----------
__global__ __launch_bounds__(256) void k_transpose(const float* __restrict__ src,
                                                   u16* __restrict__ dst) {
  __shared__ u16 tile[64][65];
  int v0 = blockIdx.x * 64, d0 = blockIdx.y * 64;
  int tid = threadIdx.x;
  int rr = tid >> 4, cc = (tid & 15) * 4;
#pragma unroll
  for (int j = 0; j < 4; ++j) {
    int r = j * 16 + rr;
    float4 f = *(const float4*)(src + (size_t)(v0 + r) * D_ + d0 + cc);
    tile[r][cc + 0] = f2bf(f.x); tile[r][cc + 1] = f2bf(f.y);
    tile[r][cc + 2] = f2bf(f.z); tile[r][cc + 3] = f2bf(f.w);
  }
  __syncthreads();
#pragma unroll
  for (int j = 0; j < 4; ++j) {
    int r = j * 16 + rr;
    ushort4 w;
    w.x = tile[cc + 0][r]; w.y = tile[cc + 1][r];
    w.z = tile[cc + 2][r]; w.w = tile[cc + 3][r];
    *(ushort4*)(dst + (size_t)(d0 + r) * V_ + v0 + cc) = w;
  }
}

// ---------------- MFMA GEMM: C[M,N] = A[M,K](lda) * B[N,K]^T, 128x128 tile ----
enum { OUT_F32 = 0, OUT_F32_ACC = 1, OUT_BF16 = 2 };

template<int OUTMODE>
__global__ __launch_bounds__(256) void k_mfma_gemm(const u16* __restrict__ A, int lda,
                                                   const u16* __restrict__ B,
                                                   void* __restrict__ Cv, int ldc, int K) {
  __shared__ u16 As[128 * 64];
  __shared__ u16 Bs[128 * 64];
  const int tid = threadIdx.x;
  const int lane = tid & 63, w = tid >> 6;
  const int wm = w >> 1, wn = w & 1;
  const int m0 = blockIdx.y * 128, n0 = blockIdx.x * 128;

  f32x4 acc[4][4] = {};

  const int srow = w * 32 + (lane >> 3);
  const int scol = (lane & 7) * 8;
  const size_t a_base = (size_t)(m0 + srow) * lda + scol;
  const size_t b_base = (size_t)(n0 + srow) * (size_t)K + scol;

  for (int kt = 0; kt < K; kt += 64) {
    __syncthreads();
#pragma unroll
    for (int i = 0; i < 4; ++i) {
      __builtin_amdgcn_global_load_lds(
          (const __attribute__((address_space(1))) void*)(A + a_base + (size_t)(i * 8) * lda + kt),
          (__attribute__((address_space(3))) void*)(&As[(w * 32 + i * 8) * 64]), 16, 0, 0);
      __builtin_amdgcn_global_load_lds(
          (const __attribute__((address_space(1))) void*)(B + b_base + (size_t)(i * 8) * K + kt),
          (__attribute__((address_space(3))) void*)(&Bs[(w * 32 + i * 8) * 64]), 16, 0, 0);
    }
    __syncthreads();
#pragma unroll
    for (int kh = 0; kh < 2; ++kh) {
      bf16x8 af[4], bfr[4];
#pragma unroll
      for (int m = 0; m < 4; ++m)
        af[m] = *(const bf16x8*)&As[(wm * 64 + m * 16 + (lane & 15)) * 64 + kh * 32 + (lane >> 4) * 8];
#pragma unroll
      for (int n = 0; n < 4; ++n)
        bfr[n] = *(const bf16x8*)&Bs[(wn * 64 + n * 16 + (lane & 15)) * 64 + kh * 32 + (lane >> 4) * 8];
#pragma unroll
      for (int m = 0; m < 4; ++m)
#pragma unroll
        for (int n = 0; n < 4; ++n)
          acc[m][n] = __builtin_amdgcn_mfma_f32_16x16x32_bf16(af[m], bfr[n], acc[m][n], 0, 0, 0);
    }
  }
  const int er = (lane >> 4) * 4;
  const int ec = lane & 15;
#pragma unroll
  for (int m = 0; m < 4; ++m)
#pragma unroll
    for (int n = 0; n < 4; ++n)
#pragma unroll
      for (int r = 0; r < 4; ++r) {
        int row = m0 + wm * 64 + m * 16 + er + r;
        int col = n0 + wn * 64 + n * 16 + ec;
        if (OUTMODE == OUT_BF16) {
          ((u16*)Cv)[(size_t)row * ldc + col] = f2bf(acc[m][n][r]);
        } else if (OUTMODE == OUT_F32_ACC) {
          ((float*)Cv)[(size_t)row * ldc + col] += acc[m][n][r];
        } else {
          ((float*)Cv)[(size_t)row * ldc + col] = acc[m][n][r];
        }
      }
}

// ---------------- LoRA ----------------
__global__ __launch_bounds__(256) void k_lora_down(const u16* __restrict__ X,
                                                   const float* __restrict__ A,
                                                   float* __restrict__ T, int nproj) {
  int s = blockIdx.x;
  int lane = threadIdx.x & 63, wv = threadIdx.x >> 6;
  const u16* x = X + (size_t)s * D_;
  for (int p = wv; p < nproj * R_; p += 4) {
    const float* a = A + (size_t)p * D_;
    float sum = 0.f;
    for (int d = lane; d < D_; d += 64) sum += bf2f(x[d]) * a[d];
#pragma unroll
    for (int m = 1; m < 64; m <<= 1) sum += __shfl_xor(sum, m, 64);
    if (lane == 0) T[(size_t)s * (nproj * R_) + p] = sum;
  }
}

__global__ __launch_bounds__(256) void k_lora_up(float* __restrict__ Y, int ystride,
                                                 const float* __restrict__ T,
                                                 const float* __restrict__ Bm, int nproj) {
  int t = blockIdx.x * 256 + threadIdx.x;
  int d = t & (D_ - 1);
  int si = t >> 11;
  int i = si % nproj;
  int s = si / nproj;
  const float* tp = T + ((size_t)s * nproj + i) * R_;
  const float* bp = Bm + ((size_t)i * D_ + d) * R_;
  float acc = 0.f;
#pragma unroll
  for (int r = 0; r < R_; r++) acc += tp[r] * bp[r];
  Y[(size_t)s * ystride + (size_t)i * D_ + d] += 2.0f * acc;
}

// ---------------- MFMA flash attention ----------------
// grid (S/64, H), 256 threads = 4 waves x 16 queries. KV tile = 64 keys.
// Swapped QK^T (mfma(K,Q)) so score col = query = lane&15 -> softmax lane-local.
__global__ __launch_bounds__(256) void k_attn_mfma(const float* __restrict__ qkv,
                                                   u16* __restrict__ out) {
  __shared__ u16 Ks[64 * 128];
  __shared__ u16 Vs[64 * 128];
  __shared__ u16 PT[4][64 * 16];
  const int tid = threadIdx.x;
  const int lane = tid & 63, w = tid >> 6;
  const int g = lane >> 4, l4 = lane & 15;
  const int q0 = blockIdx.x * 64;
  const int hh = blockIdx.y;
  const int ld = 3 * D_;
  const float rs = 0.08838834764831845f;  // 1/sqrt(128)
  char* ks_base = (char*)Ks;
  char* vs_base = (char*)Vs;
  char* pt_w = (char*)&PT[w][0];

  // Q b-fragments: col=query=l4, k-rows = dh (kh*32 + g*8 .. +7)
  bf16x8 qf[4];
  const int qglob = q0 + w * 16 + l4;
  {
    const float* qp = qkv + (size_t)qglob * ld + hh * DH_;
#pragma unroll
    for (int kh = 0; kh < 4; ++kh) {
      float4 f0 = *(const float4*)(qp + kh * 32 + g * 8);
      float4 f1 = *(const float4*)(qp + kh * 32 + g * 8 + 4);
      union { bf16x8 v; u16 s[8]; } uq;
      uq.s[0] = f2bf(f0.x); uq.s[1] = f2bf(f0.y); uq.s[2] = f2bf(f0.z); uq.s[3] = f2bf(f0.w);
      uq.s[4] = f2bf(f1.x); uq.s[5] = f2bf(f1.y); uq.s[6] = f2bf(f1.z); uq.s[7] = f2bf(f1.w);
      qf[kh] = uq.v;
    }
  }

  float m = -3.0e38f, lsum = 0.f;
  f32x4 acc_o[8] = {};

  const int nt = blockIdx.x + 1;
  for (int kt = 0; kt < nt; ++kt) {
    const int kv0 = kt * 64;
    __syncthreads();   // previous tile's LDS reads done
    // stage K,V (f32 -> bf16, swizzled): 1024 chunks of 16B each matrix
#pragma unroll
    for (int i = 0; i < 4; ++i) {
      int c = i * 256 + tid;
      int row = c >> 4, cc = c & 15;
      const float* srcK = qkv + (size_t)(kv0 + row) * ld + D_ + hh * DH_ + cc * 8;
      const float* srcV = srcK + D_;
      int byte = row * 256 + cc * 16;
      byte ^= ((row & 7) << 4) ^ (((row >> 3) & 3) << 5);
      {
        float4 f0 = *(const float4*)(srcK);
        float4 f1 = *(const float4*)(srcK + 4);
        uint4 o;
        o.x = (u32)f2bf(f0.x) | ((u32)f2bf(f0.y) << 16);
        o.y = (u32)f2bf(f0.z) | ((u32)f2bf(f0.w) << 16);
        o.z = (u32)f2bf(f1.x) | ((u32)f2bf(f1.y) << 16);
        o.w = (u32)f2bf(f1.z) | ((u32)f2bf(f1.w) << 16);
        *(uint4*)(ks_base + byte) = o;
      }
      {
        float4 f0 = *(const float4*)(srcV);
        float4 f1 = *(const float4*)(srcV + 4);
        uint4 o;
        o.x = (u32)f2bf(f0.x) | ((u32)f2bf(f0.y) << 16);
        o.y = (u32)f2bf(f0.z) | ((u32)f2bf(f0.w) << 16);
        o.z = (u32)f2bf(f1.x) | ((u32)f2bf(f1.y) << 16);
        o.w = (u32)f2bf(f1.z) | ((u32)f2bf(f1.w) << 16);
        *(uint4*)(vs_base + byte) = o;
      }
    }
    __syncthreads();

    // S^T = K · Q^T : per-wave 64 keys x 16 queries
    f32x4 sa[4] = {};
#pragma unroll
    for (int kb = 0; kb < 4; ++kb) {
#pragma unroll
      for (int kh = 0; kh < 4; ++kh) {
        int key = kb * 16 + l4;
        int byte = key * 256 + kh * 64 + g * 16;
        byte ^= ((key & 7) << 4) ^ (((key >> 3) & 3) << 5);
        bf16x8 af = *(const bf16x8*)(ks_base + byte);
        sa[kb] = __builtin_amdgcn_mfma_f32_16x16x32_bf16(af, qf[kh], sa[kb], 0, 0, 0);
      }
    }

    // online softmax (stats lane-local per query = l4)
    float p[16];
    float tmax = -3.0e38f;
#pragma unroll
    for (int kb = 0; kb < 4; ++kb)
#pragma unroll
      for (int r = 0; r < 4; ++r) {
        float s = sa[kb][r] * rs;
        int kglob = kv0 + kb * 16 + g * 4 + r;
        if (kglob > qglob) s = -1.0e30f;
        p[kb * 4 + r] = s;
        tmax = fmaxf(tmax, s);
      }
    tmax = fmaxf(tmax, __shfl_xor(tmax, 16, 64));
    tmax = fmaxf(tmax, __shfl_xor(tmax, 32, 64));
    float mnew = fmaxf(m, tmax);
    float corr = __expf(m - mnew);
    m = mnew;
    float psum = 0.f;
#pragma unroll
    for (int i = 0; i < 16; ++i) { p[i] = __expf(p[i] - mnew); psum += p[i]; }
    psum += __shfl_xor(psum, 16, 64);
    psum += __shfl_xor(psum, 32, 64);
    lsum = lsum * corr + psum;
#pragma unroll
    for (int f = 0; f < 8; ++f) {
      acc_o[f][0] *= corr; acc_o[f][1] *= corr;
      acc_o[f][2] *= corr; acc_o[f][3] *= corr;
    }

    // P^T -> wave-private LDS (swizzled)
#pragma unroll
    for (int kb = 0; kb < 4; ++kb)
#pragma unroll
      for (int r = 0; r < 4; ++r) {
        int key = kb * 16 + g * 4 + r;
        int byte = key * 32 + l4 * 2;
        byte ^= ((key >> 3) & 3) << 5;
        *(u16*)(pt_w + byte) = f2bf(p[kb * 4 + r]);
      }

    // O^T += V^T · P^T
    bf16x8 pb[2];
#pragma unroll
    for (int ks = 0; ks < 2; ++ks) {
      union { bf16x8 v; u16 s[8]; } ub;
#pragma unroll
      for (int j = 0; j < 8; ++j) {
        int key = ks * 32 + g * 8 + j;
        int byte = key * 32 + l4 * 2;
        byte ^= ((key >> 3) & 3) << 5;
        ub.s[j] = *(const u16*)(pt_w + byte);
      }
      pb[ks] = ub.v;
    }
#pragma unroll
    for (int f = 0; f < 8; ++f) {
#pragma unroll
      for (int ks = 0; ks < 2; ++ks) {
        union { bf16x8 v; u16 s[8]; } ua;
#pragma unroll
        for (int j = 0; j < 8; ++j) {
          int key = ks * 32 + g * 8 + j;
          int byte = key * 256 + (f * 16 + l4) * 2;
          byte ^= ((key & 7) << 4) ^ (((key >> 3) & 3) << 5);
          ua.s[j] = *(const u16*)(vs_base + byte);
        }
        acc_o[f] = __builtin_amdgcn_mfma_f32_16x16x32_bf16(ua.v, pb[ks], acc_o[f], 0, 0, 0);
      }
    }
  }

  float inv = 1.f / lsum;
  u16* op = out + (size_t)qglob * D_ + hh * DH_;
#pragma unroll
  for (int f = 0; f < 8; ++f)
#pragma unroll
    for (int r = 0; r < 4; ++r)
      op[f * 16 + g * 4 + r] = f2bf(acc_o[f][r] * inv);
}

// ---------------- silu(gate)*up ----------------
__global__ __launch_bounds__(256) void k_silumul(u16* __restrict__ gu) {
  size_t i = ((size_t)blockIdx.x * 256 + threadIdx.x) * 4;
  int s = (int)(i >> 13);
  int f = (int)(i & 8191);
  u16* gp = gu + (size_t)s * (2 * DFF_) + f;
  ushort4 gt = *(ushort4*)gp;
  ushort4 up = *(ushort4*)(gp + DFF_);
  float g0 = bf2f(gt.x), g1 = bf2f(gt.y), g2 = bf2f(gt.z), g3 = bf2f(gt.w);
  float u0 = bf2f(up.x), u1 = bf2f(up.y), u2 = bf2f(up.z), u3 = bf2f(up.w);
  ushort4 o;
  o.x = f2bf(g0 / (1.f + __expf(-g0)) * u0);
  o.y = f2bf(g1 / (1.f + __expf(-g1)) * u1);
  o.z = f2bf(g2 / (1.f + __expf(-g2)) * u2);
  o.w = f2bf(g3 / (1.f + __expf(-g3)) * u3);
  *(ushort4*)gp = o;
}

// ---------------- gumbel softmax -> g (bf16) ----------------
__global__ __launch_bounds__(256) void k_gumbel(const float* __restrict__ logits,
                                                const float* __restrict__ u,
                                                u16* __restrict__ g) {
  int s = blockIdx.x;
  const float* lp = logits + (size_t)s * V_;
  const float* up = u + (size_t)s * V_;
  float m = -3.0e38f, l = 0.f;
  for (int v = threadIdx.x; v < V_; v += 256) {
    float z = lp[v] - __logf(-__logf(up[v] + 1e-10f) + 1e-10f);
    float mn = fmaxf(m, z);
    l = l * __expf(m - mn) + __expf(z - mn);
    m = mn;
  }
#pragma unroll
  for (int msk = 1; msk < 64; msk <<= 1) {
    float m2 = __shfl_xor(m, msk, 64), l2 = __shfl_xor(l, msk, 64);
    float mn = fmaxf(m, m2);
    l = l * __expf(m - mn) + l2 * __expf(m2 - mn);
    m = mn;
  }
  __shared__ float shm[4], shl[4];
  if ((threadIdx.x & 63) == 0) { shm[threadIdx.x >> 6] = m; shl[threadIdx.x >> 6] = l; }
  __syncthreads();
  float M = fmaxf(fmaxf(shm[0], shm[1]), fmaxf(shm[2], shm[3]));
  float L = shl[0] * __expf(shm[0] - M) + shl[1] * __expf(shm[1] - M) +
            shl[2] * __expf(shm[2] - M) + shl[3] * __expf(shm[3] - M);
  float inv = 1.f / L;
  u16* gp = g + (size_t)s * V_;
  for (int v = threadIdx.x; v < V_; v += 256) {
    float z = lp[v] - __logf(-__logf(up[v] + 1e-10f) + 1e-10f);
    gp[v] = f2bf(__expf(z - M) * inv);
  }
}

extern "C" void kernel_launch(void* const* d_in, const int* in_sizes, int n_in,
                              void* d_out, int out_size, void* d_ws, size_t ws_size,
                              hipStream_t stream) {
  const int*   ids        = (const int*)d_in[0];
  const float* u          = (const float*)d_in[1];
  const float* emb        = (const float*)d_in[2];
  const float* attn_scale = (const float*)d_in[3];
  const float* gu_scale   = (const float*)d_in[4];
  const float* dn_scale   = (const float*)d_in[5];
  const float* lora_A     = (const float*)d_in[6];
  const float* lora_B     = (const float*)d_in[7];
  const float* norm_w     = (const float*)d_in[8];
  const float* fnorm_w    = (const float*)d_in[9];
  const int*   attn_idx   = (const int*)d_in[10];
  const int*   gu_idx     = (const int*)d_in[11];
  const int*   dn_idx     = (const int*)d_in[12];

  float* out_se = (float*)d_out;
  float* out_lg = (float*)d_out + (size_t)S_ * D_;

  char* W = (char*)d_ws;
  float* h    = (float*)(W);                          // 16 MiB
  u16*   xb   = (u16*)(W + ((size_t)16 << 20));       // 8 MiB
  float* qkv  = (float*)(W + ((size_t)24 << 20));     // 48 MiB
  u16*   ob   = (u16*)(W + ((size_t)72 << 20));       // 8 MiB
  u16*   gub  = (u16*)(W + ((size_t)80 << 20));       // 64 MiB
  u16*   wdq  = (u16*)(W + ((size_t)144 << 20));      // 64 MiB
  float* Tl   = (float*)(W + ((size_t)208 << 20));    // 192 KiB
  u16*   embb = (u16*)(W);                            // 125 MiB (head)
  u16*   gsm  = (u16*)(W + ((size_t)125 << 20));      // 125 MiB (head)
  u16*   embT = (u16*)(W);                            // 125 MiB (replaces embb)
  u16*   xbh  = (u16*)d_out;                          // final-norm out, parked in out_se

  dim3 b256(256);

  k_gather<<<dim3(S_ * D_ / 256), b256, 0, stream>>>(ids, emb, h);

  for (int l = 0; l < L_; ++l) {
    const int*   aidx = attn_idx + (size_t)l * 4 * D_ * D_;
    const float* ascl = attn_scale + (size_t)l * 4 * D_ * (D_ / 64);
    const float* lA   = lora_A + (size_t)l * 4 * R_ * D_;
    const float* lB   = lora_B + (size_t)l * 4 * D_ * R_;

    // ---- attention ----
    k_rmsnorm<<<dim3(S_), b256, 0, stream>>>(h, norm_w + (size_t)l * 2 * D_, xb);
    k_dequant<<<dim3(4 * D_ * D_ / 8 / 256), b256, 0, stream>>>(aidx, ascl, wdq, 11);
    k_mfma_gemm<OUT_F32><<<dim3(3 * D_ / 128, S_ / 128), b256, 0, stream>>>(
        xb, D_, wdq, qkv, 3 * D_, D_);
    k_lora_down<<<dim3(S_), b256, 0, stream>>>(xb, lA, Tl, 3);
    k_lora_up<<<dim3(S_ * 3 * D_ / 256), b256, 0, stream>>>(qkv, 3 * D_, Tl, lB, 3);
    k_attn_mfma<<<dim3(S_ / 64, H_), b256, 0, stream>>>(qkv, ob);
    k_mfma_gemm<OUT_F32_ACC><<<dim3(D_ / 128, S_ / 128), b256, 0, stream>>>(
        ob, D_, wdq + (size_t)3 * D_ * D_, h, D_, D_);
    k_lora_down<<<dim3(S_), b256, 0, stream>>>(ob, lA + (size_t)3 * R_ * D_, Tl, 1);
    k_lora_up<<<dim3(S_ * D_ / 256), b256, 0, stream>>>(h, D_, Tl, lB + (size_t)3 * D_ * R_, 1);

    // ---- ffn ----
    k_rmsnorm<<<dim3(S_), b256, 0, stream>>>(h, norm_w + (size_t)l * 2 * D_ + D_, xb);
    k_dequant<<<dim3(2 * DFF_ * D_ / 8 / 256), b256, 0, stream>>>(
        gu_idx + (size_t)l * 2 * DFF_ * D_, gu_scale + (size_t)l * 2 * DFF_ * (D_ / 64), wdq, 11);
    k_mfma_gemm<OUT_BF16><<<dim3(2 * DFF_ / 128, S_ / 128), b256, 0, stream>>>(
        xb, D_, wdq, gub, 2 * DFF_, D_);
    k_silumul<<<dim3(S_ * DFF_ / 4 / 256), b256, 0, stream>>>(gub);
    k_dequant<<<dim3(D_ * DFF_ / 8 / 256), b256, 0, stream>>>(
        dn_idx + (size_t)l * D_ * DFF_, dn_scale + (size_t)l * D_ * (DFF_ / 64), wdq, 13);
    k_mfma_gemm<OUT_F32_ACC><<<dim3(D_ / 128, S_ / 128), b256, 0, stream>>>(
        gub, 2 * DFF_, wdq, h, D_, DFF_);
  }

  // ---- head ----
  k_rmsnorm<<<dim3(S_), b256, 0, stream>>>(h, fnorm_w, xbh);
  k_f2b<<<dim3(V_ * D_ / 8 / 256), b256, 0, stream>>>(emb, embb);
  k_mfma_gemm<OUT_F32><<<dim3(V_ / 128, S_ / 128), b256, 0, stream>>>(
      xbh, D_, embb, out_lg, V_, D_);
  k_gumbel<<<dim3(S_), b256, 0, stream>>>(out_lg, u, gsm);
  k_transpose<<<dim3(V_ / 64, D_ / 64), b256, 0, stream>>>(emb, embT);
  k_mfma_gemm<OUT_F32><<<dim3(D_ / 128, S_ / 128), b256, 0, stream>>>(
      gsm, V_, embT, out_se, D_, V_);
}

// Round 4
// 2870.421 us; speedup vs baseline: 8.4050x; 1.3050x over previous
//
#include <hip/hip_runtime.h>
#include <hip/hip_bf16.h>

typedef unsigned short u16;
typedef unsigned int u32;
typedef __bf16 bf16t;
typedef bf16t bf16x8 __attribute__((ext_vector_type(8)));
typedef float f32x4 __attribute__((ext_vector_type(4)));

constexpr int S_   = 2048;
constexpr int D_   = 2048;
constexpr int H_   = 16;
constexpr int DH_  = 128;
constexpr int L_   = 2;
constexpr int DFF_ = 8192;
constexpr int V_   = 32000;
constexpr int R_   = 8;

__constant__ float c_nf4[16] = {
  -1.0f, -0.6961928009986877f, -0.5250730514526367f, -0.39491748809814453f,
  -0.28444138169288635f, -0.18477343022823334f, -0.09105003625154495f, 0.0f,
  0.07958029955625534f, 0.16093020141124725f, 0.24611230194568634f,
  0.33791524171829224f, 0.44070982933044434f, 0.5626170039176941f,
  0.7229568362236023f, 1.0f };

__device__ __forceinline__ u16 f2bf(float f) {
  union { float f; u32 u; } v; v.f = f;
  u32 r = v.u + 0x7fffu + ((v.u >> 16) & 1u);
  return (u16)(r >> 16);
}
__device__ __forceinline__ float bf2f(u16 h) {
  union { u32 u; float f; } v; v.u = ((u32)h) << 16; return v.f;
}

// ---------------- embedding gather ----------------
__global__ __launch_bounds__(256) void k_gather(const int* __restrict__ ids,
                                                const float* __restrict__ emb,
                                                float* __restrict__ h) {
  int t = blockIdx.x * 256 + threadIdx.x;
  int s = t >> 11;
  int d = t & 2047;
  h[t] = emb[(size_t)ids[s] * D_ + d];
}

// ---------------- rmsnorm f32 -> bf16 ----------------
__global__ __launch_bounds__(256) void k_rmsnorm(const float* __restrict__ in,
                                                 const float* __restrict__ w,
                                                 u16* __restrict__ out) {
  int s = blockIdx.x;
  const float* x = in + (size_t)s * D_;
  float ss = 0.f;
  for (int d = threadIdx.x; d < D_; d += 256) { float v = x[d]; ss += v * v; }
#pragma unroll
  for (int m = 1; m < 64; m <<= 1) ss += __shfl_xor(ss, m, 64);
  __shared__ float sh[4];
  if ((threadIdx.x & 63) == 0) sh[threadIdx.x >> 6] = ss;
  __syncthreads();
  ss = sh[0] + sh[1] + sh[2] + sh[3];
  float sc = rsqrtf(ss * (1.0f / D_) + 1e-6f);
  u16* o = out + (size_t)s * D_;
  for (int d = threadIdx.x; d < D_; d += 256) o[d] = f2bf(x[d] * sc * w[d]);
}

// ---------------- NF4 dequant ----------------
__global__ __launch_bounds__(256) void k_dequant(const int* __restrict__ idx,
                                                 const float* __restrict__ scale,
                                                 u16* __restrict__ out, int kshift) {
  size_t t = (size_t)blockIdx.x * 256 + threadIdx.x;
  size_t e = t * 8;
  int k = (int)(e & ((1u << kshift) - 1));
  size_t n = e >> kshift;
  float s = scale[(n << (kshift - 6)) + (k >> 6)];
  int4 i0 = *(const int4*)(idx + e);
  int4 i1 = *(const int4*)(idx + e + 4);
  uint4 o;
  o.x = (u32)f2bf(c_nf4[i0.x] * s) | ((u32)f2bf(c_nf4[i0.y] * s) << 16);
  o.y = (u32)f2bf(c_nf4[i0.z] * s) | ((u32)f2bf(c_nf4[i0.w] * s) << 16);
  o.z = (u32)f2bf(c_nf4[i1.x] * s) | ((u32)f2bf(c_nf4[i1.y] * s) << 16);
  o.w = (u32)f2bf(c_nf4[i1.z] * s) | ((u32)f2bf(c_nf4[i1.w] * s) << 16);
  *(uint4*)(out + e) = o;
}

// ---------------- f32 -> bf16 convert (emb) ----------------
__global__ __launch_bounds__(256) void k_f2b(const float* __restrict__ src,
                                             u16* __restrict__ dst) {
  size_t e = ((size_t)blockIdx.x * 256 + threadIdx.x) * 8;
  float4 f0 = *(const float4*)(src + e);
  float4 f1 = *(const float4*)(src + e + 4);
  uint4 o;
  o.x = (u32)f2bf(f0.x) | ((u32)f2bf(f0.y) << 16);
  o.y = (u32)f2bf(f0.z) | ((u32)f2bf(f0.w) << 16);
  o.z = (u32)f2bf(f1.x) | ((u32)f2bf(f1.y) << 16);
  o.w = (u32)f2bf(f1.z) | ((u32)f2bf(f1.w) << 16);
  *(uint4*)(dst + e) = o;
}

// ---------------- transpose-convert: emb f32 [V,D] -> embT bf16 [D,V] ----------
__global__ __launch_bounds__(256) void k_transpose(const float* __restrict__ src,
                                                   u16* __restrict__ dst) {
  __shared__ u16 tile[64][65];
  int v0 = blockIdx.x * 64, d0 = blockIdx.y * 64;
  int tid = threadIdx.x;
  int rr = tid >> 4, cc = (tid & 15) * 4;
#pragma unroll
  for (int j = 0; j < 4; ++j) {
    int r = j * 16 + rr;
    float4 f = *(const float4*)(src + (size_t)(v0 + r) * D_ + d0 + cc);
    tile[r][cc + 0] = f2bf(f.x); tile[r][cc + 1] = f2bf(f.y);
    tile[r][cc + 2] = f2bf(f.z); tile[r][cc + 3] = f2bf(f.w);
  }
  __syncthreads();
#pragma unroll
  for (int j = 0; j < 4; ++j) {
    int r = j * 16 + rr;
    ushort4 w;
    w.x = tile[cc + 0][r]; w.y = tile[cc + 1][r];
    w.z = tile[cc + 2][r]; w.w = tile[cc + 3][r];
    *(ushort4*)(dst + (size_t)(d0 + r) * V_ + v0 + cc) = w;
  }
}

// ======== 256x256 pipelined MFMA GEMM: C[M,N] = A[M,K](lda) * B[N,K]^T ========
// 512 thr = 8 waves (2M x 4N), BK=64, LDS 128 KiB double-buffered.
// 4 phases/K-tile: p1 reads A(rows0-63)+B(cols0-31) -> Q00; p2 +B(cols32-63) -> Q01;
// p3 +A(rows64-127) -> Q11; p4 (reg reuse) -> Q10. One half-tile staged per phase
// via global_load_lds(16B) with pre-swizzled source (chunk ^= row&7); boundary
// s_waitcnt vmcnt(4)+s_barrier per tile (counted, never drained in-loop).
enum { OUT_F32 = 0, OUT_F32_ACC = 1, OUT_BF16 = 2 };

template<int OUTMODE>
__global__ __launch_bounds__(512, 2) void k_gemm256(const u16* __restrict__ A, int lda,
                                                    const u16* __restrict__ B, int ldb,
                                                    void* __restrict__ Cv, int ldc,
                                                    int Kc, size_t zstride) {
  __shared__ u16 As[2][256][64];
  __shared__ u16 Bs[2][256][64];
  const int tid = threadIdx.x;
  const int lane = tid & 63, w = tid >> 6;
  const int wr = w >> 2, wc = w & 3;
  const int g = (lane >> 4), l15 = lane & 15, sl7 = lane & 7;

  // bijective XCD swizzle (gridDim.x*gridDim.y always % 8 == 0 here)
  const int nbx = gridDim.x;
  const int cpx = (nbx * gridDim.y) >> 3;
  int lin = blockIdx.y * nbx + blockIdx.x;
  int swz = (lin & 7) * cpx + (lin >> 3);
  const int m0 = (swz / nbx) * 256;
  const int n0 = (swz % nbx) * 256;

  // split-K plane
  A += (size_t)blockIdx.z * Kc;
  B += (size_t)blockIdx.z * Kc;
  float* Cf = (float*)Cv + (size_t)blockIdx.z * zstride;

  const int NT = Kc >> 6;
  const int srow = w * 8 + (lane >> 3);          // staged row within half (round 0)
  const int sch  = (lane & 7) ^ (lane >> 3);     // pre-swizzled source chunk

  // stage half `half` (0/1) of A or B for K-tile `tile` into buf[tile&1]
  auto stageA = [&](int half, int tile) {
    const u16* src = A + (size_t)(m0 + half * 128 + srow) * lda + tile * 64 + sch * 8;
    u16* dst = &As[tile & 1][half * 128 + w * 8][0];
#pragma unroll
    for (int rnd = 0; rnd < 2; ++rnd)
      __builtin_amdgcn_global_load_lds(
          (const __attribute__((address_space(1))) void*)(src + (size_t)rnd * 64 * lda),
          (__attribute__((address_space(3))) void*)(dst + rnd * 64 * 64), 16, 0, 0);
  };
  auto stageB = [&](int half, int tile) {
    const u16* src = B + (size_t)(n0 + half * 128 + srow) * ldb + tile * 64 + sch * 8;
    u16* dst = &Bs[tile & 1][half * 128 + w * 8][0];
#pragma unroll
    for (int rnd = 0; rnd < 2; ++rnd)
      __builtin_amdgcn_global_load_lds(
          (const __attribute__((address_space(1))) void*)(src + (size_t)rnd * 64 * ldb),
          (__attribute__((address_space(3))) void*)(dst + rnd * 64 * 64), 16, 0, 0);
  };

  f32x4 acc[8][4] = {};
  bf16x8 areg[4][2], breg[2][2][2];

  // prologue: tile0 fully, tile1 halves B0,A0; leave 2 halves (4 loads) in flight
  stageB(0, 0); stageA(0, 0); stageB(1, 0); stageA(1, 0);
  if (NT > 1) {
    stageB(0, 1); stageA(0, 1);
    asm volatile("s_waitcnt vmcnt(4)" ::: "memory");
  } else {
    asm volatile("s_waitcnt vmcnt(0)" ::: "memory");
  }
  __builtin_amdgcn_s_barrier();

#define LOADA(QR)                                                                   \
  _Pragma("unroll") for (int m = 0; m < 4; ++m)                                     \
    _Pragma("unroll") for (int kh = 0; kh < 2; ++kh) {                              \
      int hr = wr * 128 + (QR) * 64 + m * 16 + l15;                                 \
      areg[m][kh] = *(const bf16x8*)(abase + hr * 64 + ((((kh << 2) | g) ^ sl7) << 3)); \
    }
#define LOADB(QC)                                                                   \
  _Pragma("unroll") for (int n = 0; n < 2; ++n)                                     \
    _Pragma("unroll") for (int kh = 0; kh < 2; ++kh) {                              \
      int br = wc * 64 + (QC) * 32 + n * 16 + l15;                                  \
      breg[QC][n][kh] = *(const bf16x8*)(bbase + br * 64 + ((((kh << 2) | g) ^ sl7) << 3)); \
    }
#define QPHASE(QR, QC)                                                              \
  __builtin_amdgcn_s_setprio(1);                                                    \
  _Pragma("unroll") for (int m = 0; m < 4; ++m)                                     \
    _Pragma("unroll") for (int n = 0; n < 2; ++n)                                   \
      _Pragma("unroll") for (int kh = 0; kh < 2; ++kh)                              \
        acc[(QR) * 4 + m][(QC) * 2 + n] = __builtin_amdgcn_mfma_f32_16x16x32_bf16(  \
            areg[m][kh], breg[QC][n][kh], acc[(QR) * 4 + m][(QC) * 2 + n], 0, 0, 0); \
  __builtin_amdgcn_s_setprio(0);

  for (int t = 0; t < NT; ++t) {
    const u16* abase = &As[t & 1][0][0];
    const u16* bbase = &Bs[t & 1][0][0];
    // p1
    LOADA(0); LOADB(0);
    if (t + 1 < NT) stageB(1, t + 1);
    QPHASE(0, 0);
    __builtin_amdgcn_s_barrier();
    // p2
    LOADB(1);
    if (t + 1 < NT) stageA(1, t + 1);
    QPHASE(0, 1);
    __builtin_amdgcn_s_barrier();
    // p3
    LOADA(1);
    if (t + 2 < NT) stageB(0, t + 2);
    QPHASE(1, 1);
    __builtin_amdgcn_s_barrier();
    // p4
    if (t + 2 < NT) stageA(0, t + 2);
    QPHASE(1, 0);
    // boundary for tile t+1
    if (t + 1 < NT) {
      if (t + 1 == NT - 1) asm volatile("s_waitcnt vmcnt(0)" ::: "memory");
      else                 asm volatile("s_waitcnt vmcnt(4)" ::: "memory");
    }
    __builtin_amdgcn_s_barrier();
  }
#undef LOADA
#undef LOADB
#undef QPHASE

  const int er = g * 4;
#pragma unroll
  for (int i = 0; i < 8; ++i)
#pragma unroll
    for (int j = 0; j < 4; ++j)
#pragma unroll
      for (int r = 0; r < 4; ++r) {
        int row = m0 + wr * 128 + i * 16 + er + r;
        int col = n0 + wc * 64 + j * 16 + l15;
        if (OUTMODE == OUT_BF16) {
          ((u16*)Cv)[(size_t)row * ldc + col] = f2bf(acc[i][j][r]);
        } else if (OUTMODE == OUT_F32_ACC) {
          Cf[(size_t)row * ldc + col] += acc[i][j][r];
        } else {
          Cf[(size_t)row * ldc + col] = acc[i][j][r];
        }
      }
}

// ---------------- split-K reduce: dst (=|+=) sum of 4 planes ----------------
__global__ __launch_bounds__(256) void k_red(const float* __restrict__ P,
                                             float* __restrict__ dst, int accmode) {
  size_t i = ((size_t)blockIdx.x * 256 + threadIdx.x) * 4;
  const size_t n = (size_t)4 * 1024 * 1024;
  float4 a = *(const float4*)(P + i);
  float4 b = *(const float4*)(P + n + i);
  float4 c = *(const float4*)(P + 2 * n + i);
  float4 d = *(const float4*)(P + 3 * n + i);
  float4 r;
  r.x = (a.x + b.x) + (c.x + d.x);
  r.y = (a.y + b.y) + (c.y + d.y);
  r.z = (a.z + b.z) + (c.z + d.z);
  r.w = (a.w + b.w) + (c.w + d.w);
  if (accmode) {
    float4 o = *(const float4*)(dst + i);
    r.x += o.x; r.y += o.y; r.z += o.z; r.w += o.w;
  }
  *(float4*)(dst + i) = r;
}

// ---------------- LoRA ----------------
__global__ __launch_bounds__(256) void k_lora_down(const u16* __restrict__ X,
                                                   const float* __restrict__ A,
                                                   float* __restrict__ T, int nproj) {
  int s = blockIdx.x;
  int lane = threadIdx.x & 63, wv = threadIdx.x >> 6;
  const u16* x = X + (size_t)s * D_;
  for (int p = wv; p < nproj * R_; p += 4) {
    const float* a = A + (size_t)p * D_;
    float sum = 0.f;
    for (int d = lane; d < D_; d += 64) sum += bf2f(x[d]) * a[d];
#pragma unroll
    for (int m = 1; m < 64; m <<= 1) sum += __shfl_xor(sum, m, 64);
    if (lane == 0) T[(size_t)s * (nproj * R_) + p] = sum;
  }
}

__global__ __launch_bounds__(256) void k_lora_up(float* __restrict__ Y, int ystride,
                                                 const float* __restrict__ T,
                                                 const float* __restrict__ Bm, int nproj) {
  int t = blockIdx.x * 256 + threadIdx.x;
  int d = t & (D_ - 1);
  int si = t >> 11;
  int i = si % nproj;
  int s = si / nproj;
  const float* tp = T + ((size_t)s * nproj + i) * R_;
  const float* bp = Bm + ((size_t)i * D_ + d) * R_;
  float acc = 0.f;
#pragma unroll
  for (int r = 0; r < R_; r++) acc += tp[r] * bp[r];
  Y[(size_t)s * ystride + (size_t)i * D_ + d] += 2.0f * acc;
}

// ---------------- MFMA flash attention ----------------
__global__ __launch_bounds__(256) void k_attn_mfma(const float* __restrict__ qkv,
                                                   u16* __restrict__ out) {
  __shared__ u16 Ks[64 * 128];
  __shared__ u16 Vs[64 * 128];
  __shared__ u16 PT[4][64 * 16];
  const int tid = threadIdx.x;
  const int lane = tid & 63, w = tid >> 6;
  const int g = lane >> 4, l4 = lane & 15;
  const int q0 = blockIdx.x * 64;
  const int hh = blockIdx.y;
  const int ld = 3 * D_;
  const float rs = 0.08838834764831845f;
  char* ks_base = (char*)Ks;
  char* vs_base = (char*)Vs;
  char* pt_w = (char*)&PT[w][0];

  bf16x8 qf[4];
  const int qglob = q0 + w * 16 + l4;
  {
    const float* qp = qkv + (size_t)qglob * ld + hh * DH_;
#pragma unroll
    for (int kh = 0; kh < 4; ++kh) {
      float4 f0 = *(const float4*)(qp + kh * 32 + g * 8);
      float4 f1 = *(const float4*)(qp + kh * 32 + g * 8 + 4);
      union { bf16x8 v; u16 s[8]; } uq;
      uq.s[0] = f2bf(f0.x); uq.s[1] = f2bf(f0.y); uq.s[2] = f2bf(f0.z); uq.s[3] = f2bf(f0.w);
      uq.s[4] = f2bf(f1.x); uq.s[5] = f2bf(f1.y); uq.s[6] = f2bf(f1.z); uq.s[7] = f2bf(f1.w);
      qf[kh] = uq.v;
    }
  }

  float m = -3.0e38f, lsum = 0.f;
  f32x4 acc_o[8] = {};

  const int nt = blockIdx.x + 1;
  for (int kt = 0; kt < nt; ++kt) {
    const int kv0 = kt * 64;
    __syncthreads();
#pragma unroll
    for (int i = 0; i < 4; ++i) {
      int c = i * 256 + tid;
      int row = c >> 4, cc = c & 15;
      const float* srcK = qkv + (size_t)(kv0 + row) * ld + D_ + hh * DH_ + cc * 8;
      const float* srcV = srcK + D_;
      int byte = row * 256 + cc * 16;
      byte ^= ((row & 7) << 4) ^ (((row >> 3) & 3) << 5);
      {
        float4 f0 = *(const float4*)(srcK);
        float4 f1 = *(const float4*)(srcK + 4);
        uint4 o;
        o.x = (u32)f2bf(f0.x) | ((u32)f2bf(f0.y) << 16);
        o.y = (u32)f2bf(f0.z) | ((u32)f2bf(f0.w) << 16);
        o.z = (u32)f2bf(f1.x) | ((u32)f2bf(f1.y) << 16);
        o.w = (u32)f2bf(f1.z) | ((u32)f2bf(f1.w) << 16);
        *(uint4*)(ks_base + byte) = o;
      }
      {
        float4 f0 = *(const float4*)(srcV);
        float4 f1 = *(const float4*)(srcV + 4);
        uint4 o;
        o.x = (u32)f2bf(f0.x) | ((u32)f2bf(f0.y) << 16);
        o.y = (u32)f2bf(f0.z) | ((u32)f2bf(f0.w) << 16);
        o.z = (u32)f2bf(f1.x) | ((u32)f2bf(f1.y) << 16);
        o.w = (u32)f2bf(f1.z) | ((u32)f2bf(f1.w) << 16);
        *(uint4*)(vs_base + byte) = o;
      }
    }
    __syncthreads();

    f32x4 sa[4] = {};
#pragma unroll
    for (int kb = 0; kb < 4; ++kb) {
#pragma unroll
      for (int kh = 0; kh < 4; ++kh) {
        int key = kb * 16 + l4;
        int byte = key * 256 + kh * 64 + g * 16;
        byte ^= ((key & 7) << 4) ^ (((key >> 3) & 3) << 5);
        bf16x8 af = *(const bf16x8*)(ks_base + byte);
        sa[kb] = __builtin_amdgcn_mfma_f32_16x16x32_bf16(af, qf[kh], sa[kb], 0, 0, 0);
      }
    }

    float p[16];
    float tmax = -3.0e38f;
#pragma unroll
    for (int kb = 0; kb < 4; ++kb)
#pragma unroll
      for (int r = 0; r < 4; ++r) {
        float s = sa[kb][r] * rs;
        int kglob = kv0 + kb * 16 + g * 4 + r;
        if (kglob > qglob) s = -1.0e30f;
        p[kb * 4 + r] = s;
        tmax = fmaxf(tmax, s);
      }
    tmax = fmaxf(tmax, __shfl_xor(tmax, 16, 64));
    tmax = fmaxf(tmax, __shfl_xor(tmax, 32, 64));
    float mnew = fmaxf(m, tmax);
    float corr = __expf(m - mnew);
    m = mnew;
    float psum = 0.f;
#pragma unroll
    for (int i = 0; i < 16; ++i) { p[i] = __expf(p[i] - mnew); psum += p[i]; }
    psum += __shfl_xor(psum, 16, 64);
    psum += __shfl_xor(psum, 32, 64);
    lsum = lsum * corr + psum;
#pragma unroll
    for (int f = 0; f < 8; ++f) {
      acc_o[f][0] *= corr; acc_o[f][1] *= corr;
      acc_o[f][2] *= corr; acc_o[f][3] *= corr;
    }

#pragma unroll
    for (int kb = 0; kb < 4; ++kb)
#pragma unroll
      for (int r = 0; r < 4; ++r) {
        int key = kb * 16 + g * 4 + r;
        int byte = key * 32 + l4 * 2;
        byte ^= ((key >> 3) & 3) << 5;
        *(u16*)(pt_w + byte) = f2bf(p[kb * 4 + r]);
      }

    bf16x8 pb[2];
#pragma unroll
    for (int ks = 0; ks < 2; ++ks) {
      union { bf16x8 v; u16 s[8]; } ub;
#pragma unroll
      for (int j = 0; j < 8; ++j) {
        int key = ks * 32 + g * 8 + j;
        int byte = key * 32 + l4 * 2;
        byte ^= ((key >> 3) & 3) << 5;
        ub.s[j] = *(const u16*)(pt_w + byte);
      }
      pb[ks] = ub.v;
    }
#pragma unroll
    for (int f = 0; f < 8; ++f) {
#pragma unroll
      for (int ks = 0; ks < 2; ++ks) {
        union { bf16x8 v; u16 s[8]; } ua;
#pragma unroll
        for (int j = 0; j < 8; ++j) {
          int key = ks * 32 + g * 8 + j;
          int byte = key * 256 + (f * 16 + l4) * 2;
          byte ^= ((key & 7) << 4) ^ (((key >> 3) & 3) << 5);
          ua.s[j] = *(const u16*)(vs_base + byte);
        }
        acc_o[f] = __builtin_amdgcn_mfma_f32_16x16x32_bf16(ua.v, pb[ks], acc_o[f], 0, 0, 0);
      }
    }
  }

  float inv = 1.f / lsum;
  u16* op = out + (size_t)qglob * D_ + hh * DH_;
#pragma unroll
  for (int f = 0; f < 8; ++f)
#pragma unroll
    for (int r = 0; r < 4; ++r)
      op[f * 16 + g * 4 + r] = f2bf(acc_o[f][r] * inv);
}

// ---------------- silu(gate)*up ----------------
__global__ __launch_bounds__(256) void k_silumul(u16* __restrict__ gu) {
  size_t i = ((size_t)blockIdx.x * 256 + threadIdx.x) * 4;
  int s = (int)(i >> 13);
  int f = (int)(i & 8191);
  u16* gp = gu + (size_t)s * (2 * DFF_) + f;
  ushort4 gt = *(ushort4*)gp;
  ushort4 up = *(ushort4*)(gp + DFF_);
  float g0 = bf2f(gt.x), g1 = bf2f(gt.y), g2 = bf2f(gt.z), g3 = bf2f(gt.w);
  float u0 = bf2f(up.x), u1 = bf2f(up.y), u2 = bf2f(up.z), u3 = bf2f(up.w);
  ushort4 o;
  o.x = f2bf(g0 / (1.f + __expf(-g0)) * u0);
  o.y = f2bf(g1 / (1.f + __expf(-g1)) * u1);
  o.z = f2bf(g2 / (1.f + __expf(-g2)) * u2);
  o.w = f2bf(g3 / (1.f + __expf(-g3)) * u3);
  *(ushort4*)gp = o;
}

// ---------------- gumbel softmax -> g (bf16) ----------------
__global__ __launch_bounds__(256) void k_gumbel(const float* __restrict__ logits,
                                                const float* __restrict__ u,
                                                u16* __restrict__ g) {
  int s = blockIdx.x;
  const float* lp = logits + (size_t)s * V_;
  const float* up = u + (size_t)s * V_;
  float m = -3.0e38f, l = 0.f;
  for (int v = threadIdx.x; v < V_; v += 256) {
    float z = lp[v] - __logf(-__logf(up[v] + 1e-10f) + 1e-10f);
    float mn = fmaxf(m, z);
    l = l * __expf(m - mn) + __expf(z - mn);
    m = mn;
  }
#pragma unroll
  for (int msk = 1; msk < 64; msk <<= 1) {
    float m2 = __shfl_xor(m, msk, 64), l2 = __shfl_xor(l, msk, 64);
    float mn = fmaxf(m, m2);
    l = l * __expf(m - mn) + l2 * __expf(m2 - mn);
    m = mn;
  }
  __shared__ float shm[4], shl[4];
  if ((threadIdx.x & 63) == 0) { shm[threadIdx.x >> 6] = m; shl[threadIdx.x >> 6] = l; }
  __syncthreads();
  float M = fmaxf(fmaxf(shm[0], shm[1]), fmaxf(shm[2], shm[3]));
  float L = shl[0] * __expf(shm[0] - M) + shl[1] * __expf(shm[1] - M) +
            shl[2] * __expf(shm[2] - M) + shl[3] * __expf(shm[3] - M);
  float inv = 1.f / L;
  u16* gp = g + (size_t)s * V_;
  for (int v = threadIdx.x; v < V_; v += 256) {
    float z = lp[v] - __logf(-__logf(up[v] + 1e-10f) + 1e-10f);
    gp[v] = f2bf(__expf(z - M) * inv);
  }
}

extern "C" void kernel_launch(void* const* d_in, const int* in_sizes, int n_in,
                              void* d_out, int out_size, void* d_ws, size_t ws_size,
                              hipStream_t stream) {
  const int*   ids        = (const int*)d_in[0];
  const float* u          = (const float*)d_in[1];
  const float* emb        = (const float*)d_in[2];
  const float* attn_scale = (const float*)d_in[3];
  const float* gu_scale   = (const float*)d_in[4];
  const float* dn_scale   = (const float*)d_in[5];
  const float* lora_A     = (const float*)d_in[6];
  const float* lora_B     = (const float*)d_in[7];
  const float* norm_w     = (const float*)d_in[8];
  const float* fnorm_w    = (const float*)d_in[9];
  const int*   attn_idx   = (const int*)d_in[10];
  const int*   gu_idx     = (const int*)d_in[11];
  const int*   dn_idx     = (const int*)d_in[12];

  float* out_se = (float*)d_out;
  float* out_lg = (float*)d_out + (size_t)S_ * D_;

  char* W = (char*)d_ws;
  float* h    = (float*)(W);                          // 16 MiB
  u16*   xb   = (u16*)(W + ((size_t)16 << 20));       // 8 MiB
  float* qkv  = (float*)(W + ((size_t)24 << 20));     // 48 MiB
  u16*   ob   = (u16*)(W + ((size_t)72 << 20));       // 8 MiB
  u16*   gub  = (u16*)(W + ((size_t)80 << 20));       // 64 MiB
  u16*   wdq  = (u16*)(W + ((size_t)144 << 20));      // 64 MiB
  float* Tl   = (float*)(W + ((size_t)208 << 20));    // 192 KiB
  u16*   embb = (u16*)(W);                            // 125 MiB (head)
  u16*   gsm  = (u16*)(W + ((size_t)125 << 20));      // 125 MiB (head)
  u16*   embT = (u16*)(W);                            // 125 MiB (replaces embb)
  u16*   xbh  = (u16*)d_out;                          // final-norm out, parked in out_se
  float* Pk   = (float*)(W + ((size_t)250 << 20));    // 64 MiB split-K partials (if ws allows)
  const bool big = ws_size >= ((size_t)314 << 20);
  const size_t ZS = (size_t)4 * 1024 * 1024;          // 2048*2048 per plane

  dim3 b256(256), b512(512);

  k_gather<<<dim3(S_ * D_ / 256), b256, 0, stream>>>(ids, emb, h);

  for (int l = 0; l < L_; ++l) {
    const int*   aidx = attn_idx + (size_t)l * 4 * D_ * D_;
    const float* ascl = attn_scale + (size_t)l * 4 * D_ * (D_ / 64);
    const float* lA   = lora_A + (size_t)l * 4 * R_ * D_;
    const float* lB   = lora_B + (size_t)l * 4 * D_ * R_;

    // ---- attention ----
    k_rmsnorm<<<dim3(S_), b256, 0, stream>>>(h, norm_w + (size_t)l * 2 * D_, xb);
    k_dequant<<<dim3(4 * D_ * D_ / 8 / 256), b256, 0, stream>>>(aidx, ascl, wdq, 11);
    k_gemm256<OUT_F32><<<dim3(3 * D_ / 256, 8), b512, 0, stream>>>(
        xb, D_, wdq, D_, qkv, 3 * D_, D_, 0);
    k_lora_down<<<dim3(S_), b256, 0, stream>>>(xb, lA, Tl, 3);
    k_lora_up<<<dim3(S_ * 3 * D_ / 256), b256, 0, stream>>>(qkv, 3 * D_, Tl, lB, 3);
    k_attn_mfma<<<dim3(S_ / 64, H_), b256, 0, stream>>>(qkv, ob);
    k_gemm256<OUT_F32_ACC><<<dim3(D_ / 256, 8), b512, 0, stream>>>(
        ob, D_, wdq + (size_t)3 * D_ * D_, D_, h, D_, D_, 0);
    k_lora_down<<<dim3(S_), b256, 0, stream>>>(ob, lA + (size_t)3 * R_ * D_, Tl, 1);
    k_lora_up<<<dim3(S_ * D_ / 256), b256, 0, stream>>>(h, D_, Tl, lB + (size_t)3 * D_ * R_, 1);

    // ---- ffn ----
    k_rmsnorm<<<dim3(S_), b256, 0, stream>>>(h, norm_w + (size_t)l * 2 * D_ + D_, xb);
    k_dequant<<<dim3(2 * DFF_ * D_ / 8 / 256), b256, 0, stream>>>(
        gu_idx + (size_t)l * 2 * DFF_ * D_, gu_scale + (size_t)l * 2 * DFF_ * (D_ / 64), wdq, 11);
    k_gemm256<OUT_BF16><<<dim3(2 * DFF_ / 256, 8), b512, 0, stream>>>(
        xb, D_, wdq, D_, gub, 2 * DFF_, D_, 0);
    k_silumul<<<dim3(S_ * DFF_ / 4 / 256), b256, 0, stream>>>(gub);
    k_dequant<<<dim3(D_ * DFF_ / 8 / 256), b256, 0, stream>>>(
        dn_idx + (size_t)l * D_ * DFF_, dn_scale + (size_t)l * D_ * (DFF_ / 64), wdq, 13);
    if (big) {
      k_gemm256<OUT_F32><<<dim3(D_ / 256, 8, 4), b512, 0, stream>>>(
          gub, 2 * DFF_, wdq, DFF_, Pk, D_, DFF_ / 4, ZS);
      k_red<<<dim3(4096), b256, 0, stream>>>(Pk, h, 1);
    } else {
      k_gemm256<OUT_F32_ACC><<<dim3(D_ / 256, 8), b512, 0, stream>>>(
          gub, 2 * DFF_, wdq, DFF_, h, D_, DFF_, 0);
    }
  }

  // ---- head ----
  k_rmsnorm<<<dim3(S_), b256, 0, stream>>>(h, fnorm_w, xbh);
  k_f2b<<<dim3(V_ * D_ / 8 / 256), b256, 0, stream>>>(emb, embb);
  k_gemm256<OUT_F32><<<dim3(V_ / 256, 8), b512, 0, stream>>>(
      xbh, D_, embb, D_, out_lg, V_, D_, 0);
  k_gumbel<<<dim3(S_), b256, 0, stream>>>(out_lg, u, gsm);
  k_transpose<<<dim3(V_ / 64, D_ / 64), b256, 0, stream>>>(emb, embT);
  if (big) {
    k_gemm256<OUT_F32><<<dim3(D_ / 256, 8, 4), b512, 0, stream>>>(
        gsm, V_, embT, V_, Pk, D_, V_ / 4, ZS);
    k_red<<<dim3(4096), b256, 0, stream>>>(Pk, out_se, 0);
  } else {
    k_gemm256<OUT_F32><<<dim3(D_ / 256, 8), b512, 0, stream>>>(
        gsm, V_, embT, V_, out_se, D_, V_, 0);
  }
}

// Round 5
// 2492.609 us; speedup vs baseline: 9.6790x; 1.1516x over previous
//
#include <hip/hip_runtime.h>
#include <hip/hip_bf16.h>

typedef unsigned short u16;
typedef unsigned int u32;
typedef __bf16 bf16t;
typedef bf16t bf16x8 __attribute__((ext_vector_type(8)));
typedef float f32x4 __attribute__((ext_vector_type(4)));

constexpr int S_   = 2048;
constexpr int D_   = 2048;
constexpr int H_   = 16;
constexpr int DH_  = 128;
constexpr int L_   = 2;
constexpr int DFF_ = 8192;
constexpr int V_   = 32000;
constexpr int R_   = 8;

#define MFMA16(a, b, c) __builtin_amdgcn_mfma_f32_16x16x32_bf16(a, b, c, 0, 0, 0)

__constant__ float c_nf4[16] = {
  -1.0f, -0.6961928009986877f, -0.5250730514526367f, -0.39491748809814453f,
  -0.28444138169288635f, -0.18477343022823334f, -0.09105003625154495f, 0.0f,
  0.07958029955625534f, 0.16093020141124725f, 0.24611230194568634f,
  0.33791524171829224f, 0.44070982933044434f, 0.5626170039176941f,
  0.7229568362236023f, 1.0f };

__device__ __forceinline__ u16 f2bf(float f) {
  union { float f; u32 u; } v; v.f = f;
  u32 r = v.u + 0x7fffu + ((v.u >> 16) & 1u);
  return (u16)(r >> 16);
}
__device__ __forceinline__ float bf2f(u16 h) {
  union { u32 u; float f; } v; v.u = ((u32)h) << 16; return v.f;
}

// ---------------- embedding gather ----------------
__global__ __launch_bounds__(256) void k_gather(const int* __restrict__ ids,
                                                const float* __restrict__ emb,
                                                float* __restrict__ h) {
  int t = blockIdx.x * 256 + threadIdx.x;
  int s = t >> 11;
  int d = t & 2047;
  h[t] = emb[(size_t)ids[s] * D_ + d];
}

// ---------------- rmsnorm f32 -> bf16 ----------------
__global__ __launch_bounds__(256) void k_rmsnorm(const float* __restrict__ in,
                                                 const float* __restrict__ w,
                                                 u16* __restrict__ out) {
  int s = blockIdx.x;
  const float* x = in + (size_t)s * D_;
  float ss = 0.f;
  for (int d = threadIdx.x; d < D_; d += 256) { float v = x[d]; ss += v * v; }
#pragma unroll
  for (int m = 1; m < 64; m <<= 1) ss += __shfl_xor(ss, m, 64);
  __shared__ float sh[4];
  if ((threadIdx.x & 63) == 0) sh[threadIdx.x >> 6] = ss;
  __syncthreads();
  ss = sh[0] + sh[1] + sh[2] + sh[3];
  float sc = rsqrtf(ss * (1.0f / D_) + 1e-6f);
  u16* o = out + (size_t)s * D_;
  for (int d = threadIdx.x; d < D_; d += 256) o[d] = f2bf(x[d] * sc * w[d]);
}

// ---------------- NF4 dequant ----------------
__global__ __launch_bounds__(256) void k_dequant(const int* __restrict__ idx,
                                                 const float* __restrict__ scale,
                                                 u16* __restrict__ out, int kshift) {
  size_t t = (size_t)blockIdx.x * 256 + threadIdx.x;
  size_t e = t * 8;
  int k = (int)(e & ((1u << kshift) - 1));
  size_t n = e >> kshift;
  float s = scale[(n << (kshift - 6)) + (k >> 6)];
  int4 i0 = *(const int4*)(idx + e);
  int4 i1 = *(const int4*)(idx + e + 4);
  uint4 o;
  o.x = (u32)f2bf(c_nf4[i0.x] * s) | ((u32)f2bf(c_nf4[i0.y] * s) << 16);
  o.y = (u32)f2bf(c_nf4[i0.z] * s) | ((u32)f2bf(c_nf4[i0.w] * s) << 16);
  o.z = (u32)f2bf(c_nf4[i1.x] * s) | ((u32)f2bf(c_nf4[i1.y] * s) << 16);
  o.w = (u32)f2bf(c_nf4[i1.z] * s) | ((u32)f2bf(c_nf4[i1.w] * s) << 16);
  *(uint4*)(out + e) = o;
}

// ---------------- f32 -> bf16 convert (emb) ----------------
__global__ __launch_bounds__(256) void k_f2b(const float* __restrict__ src,
                                             u16* __restrict__ dst) {
  size_t e = ((size_t)blockIdx.x * 256 + threadIdx.x) * 8;
  float4 f0 = *(const float4*)(src + e);
  float4 f1 = *(const float4*)(src + e + 4);
  uint4 o;
  o.x = (u32)f2bf(f0.x) | ((u32)f2bf(f0.y) << 16);
  o.y = (u32)f2bf(f0.z) | ((u32)f2bf(f0.w) << 16);
  o.z = (u32)f2bf(f1.x) | ((u32)f2bf(f1.y) << 16);
  o.w = (u32)f2bf(f1.z) | ((u32)f2bf(f1.w) << 16);
  *(uint4*)(dst + e) = o;
}

// ---------------- transpose-convert: emb f32 [V,D] -> embT bf16 [D,V] ----------
__global__ __launch_bounds__(256) void k_transpose(const float* __restrict__ src,
                                                   u16* __restrict__ dst) {
  __shared__ u16 tile[64][65];
  int v0 = blockIdx.x * 64, d0 = blockIdx.y * 64;
  int tid = threadIdx.x;
  int rr = tid >> 4, cc = (tid & 15) * 4;
#pragma unroll
  for (int j = 0; j < 4; ++j) {
    int r = j * 16 + rr;
    float4 f = *(const float4*)(src + (size_t)(v0 + r) * D_ + d0 + cc);
    tile[r][cc + 0] = f2bf(f.x); tile[r][cc + 1] = f2bf(f.y);
    tile[r][cc + 2] = f2bf(f.z); tile[r][cc + 3] = f2bf(f.w);
  }
  __syncthreads();
#pragma unroll
  for (int j = 0; j < 4; ++j) {
    int r = j * 16 + rr;
    ushort4 w;
    w.x = tile[cc + 0][r]; w.y = tile[cc + 1][r];
    w.z = tile[cc + 2][r]; w.w = tile[cc + 3][r];
    *(ushort4*)(dst + (size_t)(d0 + r) * V_ + v0 + cc) = w;
  }
}

// ======== 256x256 pipelined MFMA GEMM (unchanged from round 4) ========
enum { OUT_F32 = 0, OUT_F32_ACC = 1, OUT_BF16 = 2 };

template<int OUTMODE>
__global__ __launch_bounds__(512, 2) void k_gemm256(const u16* __restrict__ A, int lda,
                                                    const u16* __restrict__ B, int ldb,
                                                    void* __restrict__ Cv, int ldc,
                                                    int Kc, size_t zstride) {
  __shared__ u16 As[2][256][64];
  __shared__ u16 Bs[2][256][64];
  const int tid = threadIdx.x;
  const int lane = tid & 63, w = tid >> 6;
  const int wr = w >> 2, wc = w & 3;
  const int g = (lane >> 4), l15 = lane & 15, sl7 = lane & 7;

  const int nbx = gridDim.x;
  const int cpx = (nbx * gridDim.y) >> 3;
  int lin = blockIdx.y * nbx + blockIdx.x;
  int swz = (lin & 7) * cpx + (lin >> 3);
  const int m0 = (swz / nbx) * 256;
  const int n0 = (swz % nbx) * 256;

  A += (size_t)blockIdx.z * Kc;
  B += (size_t)blockIdx.z * Kc;
  float* Cf = (float*)Cv + (size_t)blockIdx.z * zstride;

  const int NT = Kc >> 6;
  const int srow = w * 8 + (lane >> 3);
  const int sch  = (lane & 7) ^ (lane >> 3);

  auto stageA = [&](int half, int tile) {
    const u16* src = A + (size_t)(m0 + half * 128 + srow) * lda + tile * 64 + sch * 8;
    u16* dst = &As[tile & 1][half * 128 + w * 8][0];
#pragma unroll
    for (int rnd = 0; rnd < 2; ++rnd)
      __builtin_amdgcn_global_load_lds(
          (const __attribute__((address_space(1))) void*)(src + (size_t)rnd * 64 * lda),
          (__attribute__((address_space(3))) void*)(dst + rnd * 64 * 64), 16, 0, 0);
  };
  auto stageB = [&](int half, int tile) {
    const u16* src = B + (size_t)(n0 + half * 128 + srow) * ldb + tile * 64 + sch * 8;
    u16* dst = &Bs[tile & 1][half * 128 + w * 8][0];
#pragma unroll
    for (int rnd = 0; rnd < 2; ++rnd)
      __builtin_amdgcn_global_load_lds(
          (const __attribute__((address_space(1))) void*)(src + (size_t)rnd * 64 * ldb),
          (__attribute__((address_space(3))) void*)(dst + rnd * 64 * 64), 16, 0, 0);
  };

  f32x4 acc[8][4] = {};
  bf16x8 areg[4][2], breg[2][2][2];

  stageB(0, 0); stageA(0, 0); stageB(1, 0); stageA(1, 0);
  if (NT > 1) {
    stageB(0, 1); stageA(0, 1);
    asm volatile("s_waitcnt vmcnt(4)" ::: "memory");
  } else {
    asm volatile("s_waitcnt vmcnt(0)" ::: "memory");
  }
  __builtin_amdgcn_s_barrier();

#define LOADA(QR)                                                                   \
  _Pragma("unroll") for (int m = 0; m < 4; ++m)                                     \
    _Pragma("unroll") for (int kh = 0; kh < 2; ++kh) {                              \
      int hr = wr * 128 + (QR) * 64 + m * 16 + l15;                                 \
      areg[m][kh] = *(const bf16x8*)(abase + hr * 64 + ((((kh << 2) | g) ^ sl7) << 3)); \
    }
#define LOADB(QC)                                                                   \
  _Pragma("unroll") for (int n = 0; n < 2; ++n)                                     \
    _Pragma("unroll") for (int kh = 0; kh < 2; ++kh) {                              \
      int br = wc * 64 + (QC) * 32 + n * 16 + l15;                                  \
      breg[QC][n][kh] = *(const bf16x8*)(bbase + br * 64 + ((((kh << 2) | g) ^ sl7) << 3)); \
    }
#define QPHASE(QR, QC)                                                              \
  __builtin_amdgcn_s_setprio(1);                                                    \
  _Pragma("unroll") for (int m = 0; m < 4; ++m)                                     \
    _Pragma("unroll") for (int n = 0; n < 2; ++n)                                   \
      _Pragma("unroll") for (int kh = 0; kh < 2; ++kh)                              \
        acc[(QR) * 4 + m][(QC) * 2 + n] = __builtin_amdgcn_mfma_f32_16x16x32_bf16(  \
            areg[m][kh], breg[QC][n][kh], acc[(QR) * 4 + m][(QC) * 2 + n], 0, 0, 0); \
  __builtin_amdgcn_s_setprio(0);

  for (int t = 0; t < NT; ++t) {
    const u16* abase = &As[t & 1][0][0];
    const u16* bbase = &Bs[t & 1][0][0];
    LOADA(0); LOADB(0);
    if (t + 1 < NT) stageB(1, t + 1);
    QPHASE(0, 0);
    __builtin_amdgcn_s_barrier();
    LOADB(1);
    if (t + 1 < NT) stageA(1, t + 1);
    QPHASE(0, 1);
    __builtin_amdgcn_s_barrier();
    LOADA(1);
    if (t + 2 < NT) stageB(0, t + 2);
    QPHASE(1, 1);
    __builtin_amdgcn_s_barrier();
    if (t + 2 < NT) stageA(0, t + 2);
    QPHASE(1, 0);
    if (t + 1 < NT) {
      if (t + 1 == NT - 1) asm volatile("s_waitcnt vmcnt(0)" ::: "memory");
      else                 asm volatile("s_waitcnt vmcnt(4)" ::: "memory");
    }
    __builtin_amdgcn_s_barrier();
  }
#undef LOADA
#undef LOADB
#undef QPHASE

  const int er = g * 4;
#pragma unroll
  for (int i = 0; i < 8; ++i)
#pragma unroll
    for (int j = 0; j < 4; ++j)
#pragma unroll
      for (int r = 0; r < 4; ++r) {
        int row = m0 + wr * 128 + i * 16 + er + r;
        int col = n0 + wc * 64 + j * 16 + l15;
        if (OUTMODE == OUT_BF16) {
          ((u16*)Cv)[(size_t)row * ldc + col] = f2bf(acc[i][j][r]);
        } else if (OUTMODE == OUT_F32_ACC) {
          Cf[(size_t)row * ldc + col] += acc[i][j][r];
        } else {
          Cf[(size_t)row * ldc + col] = acc[i][j][r];
        }
      }
}

// ---------------- split-K reduce ----------------
__global__ __launch_bounds__(256) void k_red(const float* __restrict__ P,
                                             float* __restrict__ dst, int accmode) {
  size_t i = ((size_t)blockIdx.x * 256 + threadIdx.x) * 4;
  const size_t n = (size_t)4 * 1024 * 1024;
  float4 a = *(const float4*)(P + i);
  float4 b = *(const float4*)(P + n + i);
  float4 c = *(const float4*)(P + 2 * n + i);
  float4 d = *(const float4*)(P + 3 * n + i);
  float4 r;
  r.x = (a.x + b.x) + (c.x + d.x);
  r.y = (a.y + b.y) + (c.y + d.y);
  r.z = (a.z + b.z) + (c.z + d.z);
  r.w = (a.w + b.w) + (c.w + d.w);
  if (accmode) {
    float4 o = *(const float4*)(dst + i);
    r.x += o.x; r.y += o.y; r.z += o.z; r.w += o.w;
  }
  *(float4*)(dst + i) = r;
}

// ---------------- LoRA ----------------
__global__ __launch_bounds__(256) void k_lora_down(const u16* __restrict__ X,
                                                   const float* __restrict__ A,
                                                   float* __restrict__ T, int nproj) {
  int s = blockIdx.x;
  int lane = threadIdx.x & 63, wv = threadIdx.x >> 6;
  const u16* x = X + (size_t)s * D_;
  for (int p = wv; p < nproj * R_; p += 4) {
    const float* a = A + (size_t)p * D_;
    float sum = 0.f;
    for (int d = lane; d < D_; d += 64) sum += bf2f(x[d]) * a[d];
#pragma unroll
    for (int m = 1; m < 64; m <<= 1) sum += __shfl_xor(sum, m, 64);
    if (lane == 0) T[(size_t)s * (nproj * R_) + p] = sum;
  }
}

__global__ __launch_bounds__(256) void k_lora_up(float* __restrict__ Y, int ystride,
                                                 const float* __restrict__ T,
                                                 const float* __restrict__ Bm, int nproj) {
  int t = blockIdx.x * 256 + threadIdx.x;
  int d = t & (D_ - 1);
  int si = t >> 11;
  int i = si % nproj;
  int s = si / nproj;
  const float* tp = T + ((size_t)s * nproj + i) * R_;
  const float* bp = Bm + ((size_t)i * D_ + d) * R_;
  float acc = 0.f;
#pragma unroll
  for (int r = 0; r < R_; r++) acc += tp[r] * bp[r];
  Y[(size_t)s * ystride + (size_t)i * D_ + d] += 2.0f * acc;
}

// ---- LoRA-up fused into f32->bf16 convert for qkv: qkvb = bf16(qkv + lora) ----
__global__ __launch_bounds__(256) void k_lora_up_qkv(const float* __restrict__ qkv,
                                                     const float* __restrict__ T,
                                                     const float* __restrict__ Bm,
                                                     u16* __restrict__ qkvb) {
  size_t t = ((size_t)blockIdx.x * 256 + threadIdx.x) * 4;
  int c = (int)(t % 6144);
  int s = (int)(t / 6144);
  int i = c >> 11, d = c & 2047;
  const float* tp = T + ((size_t)s * 3 + i) * R_;
  float4 q = *(const float4*)(qkv + t);
  ushort4 o;
  float v[4] = {q.x, q.y, q.z, q.w};
#pragma unroll
  for (int j = 0; j < 4; ++j) {
    const float* bp = Bm + ((size_t)i * D_ + d + j) * R_;
    float acc = 0.f;
#pragma unroll
    for (int r = 0; r < R_; r++) acc += tp[r] * bp[r];
    v[j] += 2.0f * acc;
  }
  o.x = f2bf(v[0]); o.y = f2bf(v[1]); o.z = f2bf(v[2]); o.w = f2bf(v[3]);
  *(ushort4*)(qkvb + t) = o;
}

// ---- per-head V transpose: Vt[h][dh][s] = qkvb[s][4096 + h*128 + dh] ----
__global__ __launch_bounds__(256) void k_vtrans(const u16* __restrict__ qkvb,
                                                u16* __restrict__ Vt) {
  __shared__ u16 t[64][136];
  int s0 = blockIdx.x * 64, hh = blockIdx.y;
  int tid = threadIdx.x;
#pragma unroll
  for (int it = 0; it < 4; ++it) {
    int e = it * 2048 + tid * 8;
    int sr = e >> 7, sc = e & 127;
    *(uint4*)&t[sr][sc] =
        *(const uint4*)(qkvb + (size_t)(s0 + sr) * 6144 + 4096 + hh * 128 + sc);
  }
  __syncthreads();
#pragma unroll
  for (int it = 0; it < 4; ++it) {
    int q = it * 256 + tid;
    int dh = q >> 3, sc = (q & 7) * 8;
    u16 e0 = t[sc + 0][dh], e1 = t[sc + 1][dh], e2 = t[sc + 2][dh], e3 = t[sc + 3][dh];
    u16 e4 = t[sc + 4][dh], e5 = t[sc + 5][dh], e6 = t[sc + 6][dh], e7 = t[sc + 7][dh];
    uint4 o;
    o.x = (u32)e0 | ((u32)e1 << 16);
    o.y = (u32)e2 | ((u32)e3 << 16);
    o.z = (u32)e4 | ((u32)e5 << 16);
    o.w = (u32)e6 | ((u32)e7 << 16);
    *(uint4*)(Vt + ((size_t)hh * DH_ + dh) * S_ + s0 + sc) = o;
  }
}

// ======== MFMA flash attention v2 ========
// grid (16, H): block p handles q-tiles {p, 31-p} (same head) -> uniform 33-tile load,
// 256 blocks = 1/CU. K and V^T staged via global_load_lds (bf16, pre-swizzled src),
// double-buffered with issue-early prefetch; both q-sets share K/V fragments.
__global__ __launch_bounds__(256) void k_attn2(const u16* __restrict__ qkvb,
                                               const u16* __restrict__ Vt,
                                               u16* __restrict__ out) {
  __shared__ u16 Ks[2][64 * 128];
  __shared__ u16 VTs[2][128 * 64];
  __shared__ u16 PT[4][64 * 16];
  const int tid = threadIdx.x;
  const int lane = tid & 63, w = tid >> 6;
  const int g = lane >> 4, l4 = lane & 15;
  const int p = blockIdx.x;
  const int hh = blockIdx.y;
  const int ld = 6144;
  const float rs = 0.08838834764831845f;  // 1/sqrt(128)
  const int qa0 = p * 64, qb0 = (31 - p) * 64;
  const int ntb = 32 - p;
  char* pt_w = (char*)&PT[w][0];

  const int qga = qa0 + w * 16 + l4;
  const int qgb = qb0 + w * 16 + l4;

  bf16x8 qfa[4], qfb[4];
#pragma unroll
  for (int kh = 0; kh < 4; ++kh) {
    qfa[kh] = *(const bf16x8*)(qkvb + (size_t)qga * ld + hh * DH_ + kh * 32 + g * 8);
    qfb[kh] = *(const bf16x8*)(qkvb + (size_t)qgb * ld + hh * DH_ + kh * 32 + g * 8);
  }

  float ma = -3.0e38f, la = 0.f, mb = -3.0e38f, lb = 0.f;
  f32x4 acc_a[8] = {}, acc_b[8] = {};
  bf16x8 pba[2], pbb[2];

  auto stage = [&](int buf, int kt) {
    const int kv0 = kt * 64;
#pragma unroll
    for (int i = 0; i < 4; ++i) {
      int rl = (w * 4 + i) * 4 + (lane >> 4);
      int cs = (lane & 15) ^ ((rl & 7) ^ (((rl >> 3) & 3) << 1));
      __builtin_amdgcn_global_load_lds(
          (const __attribute__((address_space(1))) void*)(
              qkvb + (size_t)(kv0 + rl) * ld + 2048 + hh * DH_ + cs * 8),
          (__attribute__((address_space(3))) void*)(&Ks[buf][(w * 4 + i) * 512]), 16, 0, 0);
    }
#pragma unroll
    for (int i = 0; i < 4; ++i) {
      int dh = (w * 4 + i) * 8 + (lane >> 3);
      int cs = (lane & 7) ^ (dh & 7);
      __builtin_amdgcn_global_load_lds(
          (const __attribute__((address_space(1))) void*)(
              Vt + ((size_t)hh * DH_ + dh) * S_ + kv0 + cs * 8),
          (__attribute__((address_space(3))) void*)(&VTs[buf][(w * 4 + i) * 512]), 16, 0, 0);
    }
  };

  auto softpb = [&](f32x4* sv, float& m, float& l, f32x4* acc, int qg, bool diag,
                    int kv0, bf16x8* pb) {
    float pv[16];
    float tmax = -3.0e38f;
#pragma unroll
    for (int kb = 0; kb < 4; ++kb)
#pragma unroll
      for (int r = 0; r < 4; ++r) {
        float s = sv[kb][r] * rs;
        if (diag) {
          int kglob = kv0 + kb * 16 + g * 4 + r;
          if (kglob > qg) s = -1.0e30f;
        }
        pv[kb * 4 + r] = s;
        tmax = fmaxf(tmax, s);
      }
    tmax = fmaxf(tmax, __shfl_xor(tmax, 16, 64));
    tmax = fmaxf(tmax, __shfl_xor(tmax, 32, 64));
    float mn = fmaxf(m, tmax);
    float corr = __expf(m - mn);
    m = mn;
    float ps = 0.f;
#pragma unroll
    for (int i = 0; i < 16; ++i) { pv[i] = __expf(pv[i] - mn); ps += pv[i]; }
    ps += __shfl_xor(ps, 16, 64);
    ps += __shfl_xor(ps, 32, 64);
    l = l * corr + ps;
#pragma unroll
    for (int f = 0; f < 8; ++f) {
      acc[f][0] *= corr; acc[f][1] *= corr; acc[f][2] *= corr; acc[f][3] *= corr;
    }
#pragma unroll
    for (int kb = 0; kb < 4; ++kb)
#pragma unroll
      for (int r = 0; r < 4; ++r) {
        int key = kb * 16 + g * 4 + r;
        int byte = (key * 32 + l4 * 2) ^ (((key >> 3) & 3) << 5);
        *(u16*)(pt_w + byte) = f2bf(pv[kb * 4 + r]);
      }
#pragma unroll
    for (int ks = 0; ks < 2; ++ks) {
      union { bf16x8 v; u16 s[8]; } ub;
#pragma unroll
      for (int j = 0; j < 8; ++j) {
        int key = ks * 32 + g * 8 + j;
        int byte = (key * 32 + l4 * 2) ^ (((key >> 3) & 3) << 5);
        ub.s[j] = *(const u16*)(pt_w + byte);
      }
      pb[ks] = ub.v;
    }
  };

  stage(0, 0);
  asm volatile("s_waitcnt vmcnt(0)" ::: "memory");
  __syncthreads();

  for (int kt = 0; kt < ntb; ++kt) {
    const int kv0 = kt * 64;
    const int buf = kt & 1;
    if (kt + 1 < ntb) stage(buf ^ 1, kt + 1);

    const char* kb_base = (const char*)&Ks[buf][0];
    const char* vb_base = (const char*)&VTs[buf][0];
    const bool doa = (kt <= p);

    // S^T = K . Q^T for both q-sets (shared K fragments)
    f32x4 sa[4] = {}, sb[4] = {};
#pragma unroll
    for (int kb = 0; kb < 4; ++kb) {
#pragma unroll
      for (int kh = 0; kh < 4; ++kh) {
        int key = kb * 16 + l4;
        int ch = (kh * 4 + g) ^ ((key & 7) ^ (((key >> 3) & 3) << 1));
        bf16x8 af = *(const bf16x8*)(kb_base + key * 256 + ch * 16);
        if (doa) sa[kb] = MFMA16(af, qfa[kh], sa[kb]);
        sb[kb] = MFMA16(af, qfb[kh], sb[kb]);
      }
    }

    if (doa) softpb(sa, ma, la, acc_a, qga, kt == p, kv0, pba);
    softpb(sb, mb, lb, acc_b, qgb, kt == ntb - 1, kv0, pbb);

    // O^T += V^T . P^T (shared V^T fragments)
#pragma unroll
    for (int f = 0; f < 8; ++f) {
#pragma unroll
      for (int ks = 0; ks < 2; ++ks) {
        int dh = f * 16 + l4;
        int ch = (ks * 4 + g) ^ (dh & 7);
        bf16x8 va = *(const bf16x8*)(vb_base + dh * 128 + ch * 16);
        if (doa) acc_a[f] = MFMA16(va, pba[ks], acc_a[f]);
        acc_b[f] = MFMA16(va, pbb[ks], acc_b[f]);
      }
    }

    if (kt + 1 < ntb) {
      asm volatile("s_waitcnt vmcnt(0)" ::: "memory");
      __syncthreads();
    }
  }

  float inva = 1.f / la, invb = 1.f / lb;
  u16* opa = out + (size_t)qga * D_ + hh * DH_;
  u16* opb = out + (size_t)qgb * D_ + hh * DH_;
#pragma unroll
  for (int f = 0; f < 8; ++f)
#pragma unroll
    for (int r = 0; r < 4; ++r) {
      opa[f * 16 + g * 4 + r] = f2bf(acc_a[f][r] * inva);
      opb[f * 16 + g * 4 + r] = f2bf(acc_b[f][r] * invb);
    }
}

// ---------------- silu(gate)*up ----------------
__global__ __launch_bounds__(256) void k_silumul(u16* __restrict__ gu) {
  size_t i = ((size_t)blockIdx.x * 256 + threadIdx.x) * 4;
  int s = (int)(i >> 13);
  int f = (int)(i & 8191);
  u16* gp = gu + (size_t)s * (2 * DFF_) + f;
  ushort4 gt = *(ushort4*)gp;
  ushort4 up = *(ushort4*)(gp + DFF_);
  float g0 = bf2f(gt.x), g1 = bf2f(gt.y), g2 = bf2f(gt.z), g3 = bf2f(gt.w);
  float u0 = bf2f(up.x), u1 = bf2f(up.y), u2 = bf2f(up.z), u3 = bf2f(up.w);
  ushort4 o;
  o.x = f2bf(g0 / (1.f + __expf(-g0)) * u0);
  o.y = f2bf(g1 / (1.f + __expf(-g1)) * u1);
  o.z = f2bf(g2 / (1.f + __expf(-g2)) * u2);
  o.w = f2bf(g3 / (1.f + __expf(-g3)) * u3);
  *(ushort4*)gp = o;
}

// ---------------- gumbel softmax -> g (bf16) ----------------
__global__ __launch_bounds__(256) void k_gumbel(const float* __restrict__ logits,
                                                const float* __restrict__ u,
                                                u16* __restrict__ g) {
  int s = blockIdx.x;
  const float* lp = logits + (size_t)s * V_;
  const float* up = u + (size_t)s * V_;
  float m = -3.0e38f, l = 0.f;
  for (int v = threadIdx.x; v < V_; v += 256) {
    float z = lp[v] - __logf(-__logf(up[v] + 1e-10f) + 1e-10f);
    float mn = fmaxf(m, z);
    l = l * __expf(m - mn) + __expf(z - mn);
    m = mn;
  }
#pragma unroll
  for (int msk = 1; msk < 64; msk <<= 1) {
    float m2 = __shfl_xor(m, msk, 64), l2 = __shfl_xor(l, msk, 64);
    float mn = fmaxf(m, m2);
    l = l * __expf(m - mn) + l2 * __expf(m2 - mn);
    m = mn;
  }
  __shared__ float shm[4], shl[4];
  if ((threadIdx.x & 63) == 0) { shm[threadIdx.x >> 6] = m; shl[threadIdx.x >> 6] = l; }
  __syncthreads();
  float M = fmaxf(fmaxf(shm[0], shm[1]), fmaxf(shm[2], shm[3]));
  float L = shl[0] * __expf(shm[0] - M) + shl[1] * __expf(shm[1] - M) +
            shl[2] * __expf(shm[2] - M) + shl[3] * __expf(shm[3] - M);
  float inv = 1.f / L;
  u16* gp = g + (size_t)s * V_;
  for (int v = threadIdx.x; v < V_; v += 256) {
    float z = lp[v] - __logf(-__logf(up[v] + 1e-10f) + 1e-10f);
    gp[v] = f2bf(__expf(z - M) * inv);
  }
}

extern "C" void kernel_launch(void* const* d_in, const int* in_sizes, int n_in,
                              void* d_out, int out_size, void* d_ws, size_t ws_size,
                              hipStream_t stream) {
  const int*   ids        = (const int*)d_in[0];
  const float* u          = (const float*)d_in[1];
  const float* emb        = (const float*)d_in[2];
  const float* attn_scale = (const float*)d_in[3];
  const float* gu_scale   = (const float*)d_in[4];
  const float* dn_scale   = (const float*)d_in[5];
  const float* lora_A     = (const float*)d_in[6];
  const float* lora_B     = (const float*)d_in[7];
  const float* norm_w     = (const float*)d_in[8];
  const float* fnorm_w    = (const float*)d_in[9];
  const int*   attn_idx   = (const int*)d_in[10];
  const int*   gu_idx     = (const int*)d_in[11];
  const int*   dn_idx     = (const int*)d_in[12];

  float* out_se = (float*)d_out;
  float* out_lg = (float*)d_out + (size_t)S_ * D_;

  char* W = (char*)d_ws;
  float* h    = (float*)(W);                          // 16 MiB
  u16*   xb   = (u16*)(W + ((size_t)16 << 20));       // 8 MiB
  float* qkv  = (float*)(W + ((size_t)24 << 20));     // 48 MiB
  u16*   qkvb = (u16*)(W + ((size_t)72 << 20));       // 24 MiB
  u16*   Vtb  = (u16*)(W + ((size_t)96 << 20));       // 8 MiB
  u16*   ob   = (u16*)(W + ((size_t)104 << 20));      // 8 MiB
  u16*   gub  = (u16*)(W + ((size_t)112 << 20));      // 64 MiB
  u16*   wdq  = (u16*)(W + ((size_t)176 << 20));      // 64 MiB
  float* Tl   = (float*)(W + ((size_t)240 << 20));    // 192 KiB
  u16*   embb = (u16*)(W);                            // 125 MiB (head)
  u16*   gsm  = (u16*)(W + ((size_t)125 << 20));      // 125 MiB (head)
  u16*   embT = (u16*)(W);                            // 125 MiB (replaces embb)
  u16*   xbh  = (u16*)d_out;                          // final-norm out, parked in out_se
  float* Pk   = (float*)(W + ((size_t)250 << 20));    // 64 MiB split-K partials
  const bool big = ws_size >= ((size_t)314 << 20);
  const size_t ZS = (size_t)4 * 1024 * 1024;

  dim3 b256(256), b512(512);

  k_gather<<<dim3(S_ * D_ / 256), b256, 0, stream>>>(ids, emb, h);

  for (int l = 0; l < L_; ++l) {
    const int*   aidx = attn_idx + (size_t)l * 4 * D_ * D_;
    const float* ascl = attn_scale + (size_t)l * 4 * D_ * (D_ / 64);
    const float* lA   = lora_A + (size_t)l * 4 * R_ * D_;
    const float* lB   = lora_B + (size_t)l * 4 * D_ * R_;

    // ---- attention ----
    k_rmsnorm<<<dim3(S_), b256, 0, stream>>>(h, norm_w + (size_t)l * 2 * D_, xb);
    k_dequant<<<dim3(4 * D_ * D_ / 8 / 256), b256, 0, stream>>>(aidx, ascl, wdq, 11);
    k_gemm256<OUT_F32><<<dim3(3 * D_ / 256, 8), b512, 0, stream>>>(
        xb, D_, wdq, D_, qkv, 3 * D_, D_, 0);
    k_lora_down<<<dim3(S_), b256, 0, stream>>>(xb, lA, Tl, 3);
    k_lora_up_qkv<<<dim3(S_ * 3 * D_ / 4 / 256), b256, 0, stream>>>(qkv, Tl, lB, qkvb);
    k_vtrans<<<dim3(S_ / 64, H_), b256, 0, stream>>>(qkvb, Vtb);
    k_attn2<<<dim3(16, H_), b256, 0, stream>>>(qkvb, Vtb, ob);
    k_gemm256<OUT_F32_ACC><<<dim3(D_ / 256, 8), b512, 0, stream>>>(
        ob, D_, wdq + (size_t)3 * D_ * D_, D_, h, D_, D_, 0);
    k_lora_down<<<dim3(S_), b256, 0, stream>>>(ob, lA + (size_t)3 * R_ * D_, Tl, 1);
    k_lora_up<<<dim3(S_ * D_ / 256), b256, 0, stream>>>(h, D_, Tl, lB + (size_t)3 * D_ * R_, 1);

    // ---- ffn ----
    k_rmsnorm<<<dim3(S_), b256, 0, stream>>>(h, norm_w + (size_t)l * 2 * D_ + D_, xb);
    k_dequant<<<dim3(2 * DFF_ * D_ / 8 / 256), b256, 0, stream>>>(
        gu_idx + (size_t)l * 2 * DFF_ * D_, gu_scale + (size_t)l * 2 * DFF_ * (D_ / 64), wdq, 11);
    k_gemm256<OUT_BF16><<<dim3(2 * DFF_ / 256, 8), b512, 0, stream>>>(
        xb, D_, wdq, D_, gub, 2 * DFF_, D_, 0);
    k_silumul<<<dim3(S_ * DFF_ / 4 / 256), b256, 0, stream>>>(gub);
    k_dequant<<<dim3(D_ * DFF_ / 8 / 256), b256, 0, stream>>>(
        dn_idx + (size_t)l * D_ * DFF_, dn_scale + (size_t)l * D_ * (DFF_ / 64), wdq, 13);
    if (big) {
      k_gemm256<OUT_F32><<<dim3(D_ / 256, 8, 4), b512, 0, stream>>>(
          gub, 2 * DFF_, wdq, DFF_, Pk, D_, DFF_ / 4, ZS);
      k_red<<<dim3(4096), b256, 0, stream>>>(Pk, h, 1);
    } else {
      k_gemm256<OUT_F32_ACC><<<dim3(D_ / 256, 8), b512, 0, stream>>>(
          gub, 2 * DFF_, wdq, DFF_, h, D_, DFF_, 0);
    }
  }

  // ---- head ----
  k_rmsnorm<<<dim3(S_), b256, 0, stream>>>(h, fnorm_w, xbh);
  k_f2b<<<dim3(V_ * D_ / 8 / 256), b256, 0, stream>>>(emb, embb);
  k_gemm256<OUT_F32><<<dim3(V_ / 256, 8), b512, 0, stream>>>(
      xbh, D_, embb, D_, out_lg, V_, D_, 0);
  k_gumbel<<<dim3(S_), b256, 0, stream>>>(out_lg, u, gsm);
  k_transpose<<<dim3(V_ / 64, D_ / 64), b256, 0, stream>>>(emb, embT);
  if (big) {
    k_gemm256<OUT_F32><<<dim3(D_ / 256, 8, 4), b512, 0, stream>>>(
        gsm, V_, embT, V_, Pk, D_, V_ / 4, ZS);
    k_red<<<dim3(4096), b256, 0, stream>>>(Pk, out_se, 0);
  } else {
    k_gemm256<OUT_F32><<<dim3(D_ / 256, 8), b512, 0, stream>>>(
        gsm, V_, embT, V_, out_se, D_, V_, 0);
  }
}

// Round 6
// 2460.573 us; speedup vs baseline: 9.8050x; 1.0130x over previous
//
#include <hip/hip_runtime.h>
#include <hip/hip_bf16.h>

typedef unsigned short u16;
typedef unsigned int u32;
typedef __bf16 bf16t;
typedef bf16t bf16x8 __attribute__((ext_vector_type(8)));
typedef float f32x4 __attribute__((ext_vector_type(4)));

constexpr int S_   = 2048;
constexpr int D_   = 2048;
constexpr int H_   = 16;
constexpr int DH_  = 128;
constexpr int L_   = 2;
constexpr int DFF_ = 8192;
constexpr int V_   = 32000;
constexpr int R_   = 8;

#define MFMA16(a, b, c) __builtin_amdgcn_mfma_f32_16x16x32_bf16(a, b, c, 0, 0, 0)

__constant__ float c_nf4[16] = {
  -1.0f, -0.6961928009986877f, -0.5250730514526367f, -0.39491748809814453f,
  -0.28444138169288635f, -0.18477343022823334f, -0.09105003625154495f, 0.0f,
  0.07958029955625534f, 0.16093020141124725f, 0.24611230194568634f,
  0.33791524171829224f, 0.44070982933044434f, 0.5626170039176941f,
  0.7229568362236023f, 1.0f };

__device__ __forceinline__ u16 f2bf(float f) {
  union { float f; u32 u; } v; v.f = f;
  u32 r = v.u + 0x7fffu + ((v.u >> 16) & 1u);
  return (u16)(r >> 16);
}
__device__ __forceinline__ float bf2f(u16 h) {
  union { u32 u; float f; } v; v.u = ((u32)h) << 16; return v.f;
}

// ---------------- embedding gather ----------------
__global__ __launch_bounds__(256) void k_gather(const int* __restrict__ ids,
                                                const float* __restrict__ emb,
                                                float* __restrict__ h) {
  int t = blockIdx.x * 256 + threadIdx.x;
  int s = t >> 11;
  int d = t & 2047;
  h[t] = emb[(size_t)ids[s] * D_ + d];
}

// ---------------- rmsnorm f32 -> bf16 ----------------
__global__ __launch_bounds__(256) void k_rmsnorm(const float* __restrict__ in,
                                                 const float* __restrict__ w,
                                                 u16* __restrict__ out) {
  int s = blockIdx.x;
  const float* x = in + (size_t)s * D_;
  float ss = 0.f;
  for (int d = threadIdx.x; d < D_; d += 256) { float v = x[d]; ss += v * v; }
#pragma unroll
  for (int m = 1; m < 64; m <<= 1) ss += __shfl_xor(ss, m, 64);
  __shared__ float sh[4];
  if ((threadIdx.x & 63) == 0) sh[threadIdx.x >> 6] = ss;
  __syncthreads();
  ss = sh[0] + sh[1] + sh[2] + sh[3];
  float sc = rsqrtf(ss * (1.0f / D_) + 1e-6f);
  u16* o = out + (size_t)s * D_;
  for (int d = threadIdx.x; d < D_; d += 256) o[d] = f2bf(x[d] * sc * w[d]);
}

// ---------------- NF4 dequant ----------------
__global__ __launch_bounds__(256) void k_dequant(const int* __restrict__ idx,
                                                 const float* __restrict__ scale,
                                                 u16* __restrict__ out, int kshift) {
  size_t t = (size_t)blockIdx.x * 256 + threadIdx.x;
  size_t e = t * 8;
  int k = (int)(e & ((1u << kshift) - 1));
  size_t n = e >> kshift;
  float s = scale[(n << (kshift - 6)) + (k >> 6)];
  int4 i0 = *(const int4*)(idx + e);
  int4 i1 = *(const int4*)(idx + e + 4);
  uint4 o;
  o.x = (u32)f2bf(c_nf4[i0.x] * s) | ((u32)f2bf(c_nf4[i0.y] * s) << 16);
  o.y = (u32)f2bf(c_nf4[i0.z] * s) | ((u32)f2bf(c_nf4[i0.w] * s) << 16);
  o.z = (u32)f2bf(c_nf4[i1.x] * s) | ((u32)f2bf(c_nf4[i1.y] * s) << 16);
  o.w = (u32)f2bf(c_nf4[i1.z] * s) | ((u32)f2bf(c_nf4[i1.w] * s) << 16);
  *(uint4*)(out + e) = o;
}

// ---------------- f32 -> bf16 convert (emb) ----------------
__global__ __launch_bounds__(256) void k_f2b(const float* __restrict__ src,
                                             u16* __restrict__ dst) {
  size_t e = ((size_t)blockIdx.x * 256 + threadIdx.x) * 8;
  float4 f0 = *(const float4*)(src + e);
  float4 f1 = *(const float4*)(src + e + 4);
  uint4 o;
  o.x = (u32)f2bf(f0.x) | ((u32)f2bf(f0.y) << 16);
  o.y = (u32)f2bf(f0.z) | ((u32)f2bf(f0.w) << 16);
  o.z = (u32)f2bf(f1.x) | ((u32)f2bf(f1.y) << 16);
  o.w = (u32)f2bf(f1.z) | ((u32)f2bf(f1.w) << 16);
  *(uint4*)(dst + e) = o;
}

// ---------------- transpose-convert: emb f32 [V,D] -> embT bf16 [D,V] ----------
__global__ __launch_bounds__(256) void k_transpose(const float* __restrict__ src,
                                                   u16* __restrict__ dst) {
  __shared__ u16 tile[64][65];
  int v0 = blockIdx.x * 64, d0 = blockIdx.y * 64;
  int tid = threadIdx.x;
  int rr = tid >> 4, cc = (tid & 15) * 4;
#pragma unroll
  for (int j = 0; j < 4; ++j) {
    int r = j * 16 + rr;
    float4 f = *(const float4*)(src + (size_t)(v0 + r) * D_ + d0 + cc);
    tile[r][cc + 0] = f2bf(f.x); tile[r][cc + 1] = f2bf(f.y);
    tile[r][cc + 2] = f2bf(f.z); tile[r][cc + 3] = f2bf(f.w);
  }
  __syncthreads();
#pragma unroll
  for (int j = 0; j < 4; ++j) {
    int r = j * 16 + rr;
    ushort4 w;
    w.x = tile[cc + 0][r]; w.y = tile[cc + 1][r];
    w.z = tile[cc + 2][r]; w.w = tile[cc + 3][r];
    *(ushort4*)(dst + (size_t)(d0 + r) * V_ + v0 + cc) = w;
  }
}

// ======== 256x256 pipelined MFMA GEMM, deep-prefetch 2-barrier phases ========
// 512 thr = 8 waves (2M x 4N), BK=64, LDS 128 KiB double-buffered.
// Tile t+2 fully staged at phases 3/4 of tile t (B halves free after p2, A after p3)
// -> 5-8 phases of slack per stage; boundary vmcnt(8) counted (= t+2's in-flight).
// Each phase: {ds_reads; stage-issue; barrier; lgkmcnt(0); setprio MFMA; barrier}.
enum { OUT_F32 = 0, OUT_F32_ACC = 1, OUT_BF16 = 2 };

template<int OUTMODE>
__global__ __launch_bounds__(512, 2) void k_gemm256(const u16* __restrict__ A, int lda,
                                                    const u16* __restrict__ B, int ldb,
                                                    void* __restrict__ Cv, int ldc,
                                                    int Kc, size_t zstride) {
  __shared__ u16 As[2][256][64];
  __shared__ u16 Bs[2][256][64];
  const int tid = threadIdx.x;
  const int lane = tid & 63, w = tid >> 6;
  const int wr = w >> 2, wc = w & 3;
  const int g = (lane >> 4), l15 = lane & 15, sl7 = lane & 7;

  // XCD swizzle, N-major within chunk: all gy M-blocks of an N-panel on one XCD
  const int gx = gridDim.x, gy = gridDim.y;
  const int cpx = (gx * gy) >> 3;
  int d = blockIdx.y * gx + blockIdx.x;
  int swz = (d & 7) * cpx + (d >> 3);
  const int m0 = (swz % gy) * 256;
  const int n0 = (swz / gy) * 256;

  A += (size_t)blockIdx.z * Kc;
  B += (size_t)blockIdx.z * Kc;
  float* Cf = (float*)Cv + (size_t)blockIdx.z * zstride;

  const int NT = Kc >> 6;
  const int srow = w * 8 + (lane >> 3);
  const int sch  = (lane & 7) ^ (lane >> 3);

  auto stageA = [&](int half, int tile) {
    const u16* src = A + (size_t)(m0 + half * 128 + srow) * lda + tile * 64 + sch * 8;
    u16* dst = &As[tile & 1][half * 128 + w * 8][0];
#pragma unroll
    for (int rnd = 0; rnd < 2; ++rnd)
      __builtin_amdgcn_global_load_lds(
          (const __attribute__((address_space(1))) void*)(src + (size_t)rnd * 64 * lda),
          (__attribute__((address_space(3))) void*)(dst + rnd * 64 * 64), 16, 0, 0);
  };
  auto stageB = [&](int half, int tile) {
    const u16* src = B + (size_t)(n0 + half * 128 + srow) * ldb + tile * 64 + sch * 8;
    u16* dst = &Bs[tile & 1][half * 128 + w * 8][0];
#pragma unroll
    for (int rnd = 0; rnd < 2; ++rnd)
      __builtin_amdgcn_global_load_lds(
          (const __attribute__((address_space(1))) void*)(src + (size_t)rnd * 64 * ldb),
          (__attribute__((address_space(3))) void*)(dst + rnd * 64 * 64), 16, 0, 0);
  };

  f32x4 acc[8][4] = {};
  bf16x8 areg[4][2], breg[2][2][2];

  // prologue: tiles 0 and 1 fully staged; vmcnt(8) => tile0 arrived
  stageB(0, 0); stageB(1, 0); stageA(0, 0); stageA(1, 0);
  if (NT > 1) {
    stageB(0, 1); stageB(1, 1); stageA(0, 1); stageA(1, 1);
    asm volatile("s_waitcnt vmcnt(8)" ::: "memory");
  } else {
    asm volatile("s_waitcnt vmcnt(0)" ::: "memory");
  }
  __builtin_amdgcn_s_barrier();

#define LOADA(QR)                                                                   \
  _Pragma("unroll") for (int m = 0; m < 4; ++m)                                     \
    _Pragma("unroll") for (int kh = 0; kh < 2; ++kh) {                              \
      int hr = wr * 128 + (QR) * 64 + m * 16 + l15;                                 \
      areg[m][kh] = *(const bf16x8*)(abase + hr * 64 + ((((kh << 2) | g) ^ sl7) << 3)); \
    }
#define LOADB(QC)                                                                   \
  _Pragma("unroll") for (int n = 0; n < 2; ++n)                                     \
    _Pragma("unroll") for (int kh = 0; kh < 2; ++kh) {                              \
      int br = wc * 64 + (QC) * 32 + n * 16 + l15;                                  \
      breg[QC][n][kh] = *(const bf16x8*)(bbase + br * 64 + ((((kh << 2) | g) ^ sl7) << 3)); \
    }
#define QPHASE(QR, QC)                                                              \
  __builtin_amdgcn_s_setprio(1);                                                    \
  _Pragma("unroll") for (int m = 0; m < 4; ++m)                                     \
    _Pragma("unroll") for (int n = 0; n < 2; ++n)                                   \
      _Pragma("unroll") for (int kh = 0; kh < 2; ++kh)                              \
        acc[(QR) * 4 + m][(QC) * 2 + n] = __builtin_amdgcn_mfma_f32_16x16x32_bf16(  \
            areg[m][kh], breg[QC][n][kh], acc[(QR) * 4 + m][(QC) * 2 + n], 0, 0, 0); \
  __builtin_amdgcn_s_setprio(0);

  for (int t = 0; t < NT; ++t) {
    const u16* abase = &As[t & 1][0][0];
    const u16* bbase = &Bs[t & 1][0][0];
    // phase 1: Q00
    LOADA(0); LOADB(0);
    __builtin_amdgcn_s_barrier();
    asm volatile("s_waitcnt lgkmcnt(0)" ::: "memory");
    QPHASE(0, 0);
    __builtin_amdgcn_s_barrier();
    // phase 2: Q01
    LOADB(1);
    __builtin_amdgcn_s_barrier();
    asm volatile("s_waitcnt lgkmcnt(0)" ::: "memory");
    QPHASE(0, 1);
    __builtin_amdgcn_s_barrier();
    // phase 3: Q11 (+ stage both B halves of t+2; B of tile t fully read after p2)
    LOADA(1);
    if (t + 2 < NT) { stageB(0, t + 2); stageB(1, t + 2); }
    __builtin_amdgcn_s_barrier();
    asm volatile("s_waitcnt lgkmcnt(0)" ::: "memory");
    QPHASE(1, 1);
    __builtin_amdgcn_s_barrier();
    // phase 4: Q10 (+ stage both A halves of t+2; A fully read after p3), boundary
    if (t + 2 < NT) { stageA(0, t + 2); stageA(1, t + 2); }
    QPHASE(1, 0);
    if (t + 1 < NT) {
      if (t + 2 < NT) asm volatile("s_waitcnt vmcnt(8)" ::: "memory");
      else            asm volatile("s_waitcnt vmcnt(0)" ::: "memory");
    }
    __builtin_amdgcn_s_barrier();
  }
#undef LOADA
#undef LOADB
#undef QPHASE

  const int er = g * 4;
#pragma unroll
  for (int i = 0; i < 8; ++i)
#pragma unroll
    for (int j = 0; j < 4; ++j)
#pragma unroll
      for (int r = 0; r < 4; ++r) {
        int row = m0 + wr * 128 + i * 16 + er + r;
        int col = n0 + wc * 64 + j * 16 + l15;
        if (OUTMODE == OUT_BF16) {
          ((u16*)Cv)[(size_t)row * ldc + col] = f2bf(acc[i][j][r]);
        } else if (OUTMODE == OUT_F32_ACC) {
          Cf[(size_t)row * ldc + col] += acc[i][j][r];
        } else {
          Cf[(size_t)row * ldc + col] = acc[i][j][r];
        }
      }
}

// ---------------- split-K reduce ----------------
__global__ __launch_bounds__(256) void k_red(const float* __restrict__ P,
                                             float* __restrict__ dst, int accmode) {
  size_t i = ((size_t)blockIdx.x * 256 + threadIdx.x) * 4;
  const size_t n = (size_t)4 * 1024 * 1024;
  float4 a = *(const float4*)(P + i);
  float4 b = *(const float4*)(P + n + i);
  float4 c = *(const float4*)(P + 2 * n + i);
  float4 d = *(const float4*)(P + 3 * n + i);
  float4 r;
  r.x = (a.x + b.x) + (c.x + d.x);
  r.y = (a.y + b.y) + (c.y + d.y);
  r.z = (a.z + b.z) + (c.z + d.z);
  r.w = (a.w + b.w) + (c.w + d.w);
  if (accmode) {
    float4 o = *(const float4*)(dst + i);
    r.x += o.x; r.y += o.y; r.z += o.z; r.w += o.w;
  }
  *(float4*)(dst + i) = r;
}

// ---------------- LoRA ----------------
__global__ __launch_bounds__(256) void k_lora_down(const u16* __restrict__ X,
                                                   const float* __restrict__ A,
                                                   float* __restrict__ T, int nproj) {
  int s = blockIdx.x;
  int lane = threadIdx.x & 63, wv = threadIdx.x >> 6;
  const u16* x = X + (size_t)s * D_;
  for (int p = wv; p < nproj * R_; p += 4) {
    const float* a = A + (size_t)p * D_;
    float sum = 0.f;
    for (int d = lane; d < D_; d += 64) sum += bf2f(x[d]) * a[d];
#pragma unroll
    for (int m = 1; m < 64; m <<= 1) sum += __shfl_xor(sum, m, 64);
    if (lane == 0) T[(size_t)s * (nproj * R_) + p] = sum;
  }
}

__global__ __launch_bounds__(256) void k_lora_up(float* __restrict__ Y, int ystride,
                                                 const float* __restrict__ T,
                                                 const float* __restrict__ Bm, int nproj) {
  int t = blockIdx.x * 256 + threadIdx.x;
  int d = t & (D_ - 1);
  int si = t >> 11;
  int i = si % nproj;
  int s = si / nproj;
  const float* tp = T + ((size_t)s * nproj + i) * R_;
  const float* bp = Bm + ((size_t)i * D_ + d) * R_;
  float acc = 0.f;
#pragma unroll
  for (int r = 0; r < R_; r++) acc += tp[r] * bp[r];
  Y[(size_t)s * ystride + (size_t)i * D_ + d] += 2.0f * acc;
}

// ---- LoRA-up fused into f32->bf16 convert for qkv: qkvb = bf16(qkv + lora) ----
__global__ __launch_bounds__(256) void k_lora_up_qkv(const float* __restrict__ qkv,
                                                     const float* __restrict__ T,
                                                     const float* __restrict__ Bm,
                                                     u16* __restrict__ qkvb) {
  size_t t = ((size_t)blockIdx.x * 256 + threadIdx.x) * 4;
  int c = (int)(t % 6144);
  int s = (int)(t / 6144);
  int i = c >> 11, d = c & 2047;
  const float* tp = T + ((size_t)s * 3 + i) * R_;
  float4 q = *(const float4*)(qkv + t);
  ushort4 o;
  float v[4] = {q.x, q.y, q.z, q.w};
#pragma unroll
  for (int j = 0; j < 4; ++j) {
    const float* bp = Bm + ((size_t)i * D_ + d + j) * R_;
    float acc = 0.f;
#pragma unroll
    for (int r = 0; r < R_; r++) acc += tp[r] * bp[r];
    v[j] += 2.0f * acc;
  }
  o.x = f2bf(v[0]); o.y = f2bf(v[1]); o.z = f2bf(v[2]); o.w = f2bf(v[3]);
  *(ushort4*)(qkvb + t) = o;
}

// ---- per-head V transpose: Vt[h][dh][s] = qkvb[s][4096 + h*128 + dh] ----
__global__ __launch_bounds__(256) void k_vtrans(const u16* __restrict__ qkvb,
                                                u16* __restrict__ Vt) {
  __shared__ u16 t[64][136];
  int s0 = blockIdx.x * 64, hh = blockIdx.y;
  int tid = threadIdx.x;
#pragma unroll
  for (int it = 0; it < 4; ++it) {
    int e = it * 2048 + tid * 8;
    int sr = e >> 7, sc = e & 127;
    *(uint4*)&t[sr][sc] =
        *(const uint4*)(qkvb + (size_t)(s0 + sr) * 6144 + 4096 + hh * 128 + sc);
  }
  __syncthreads();
#pragma unroll
  for (int it = 0; it < 4; ++it) {
    int q = it * 256 + tid;
    int dh = q >> 3, sc = (q & 7) * 8;
    u16 e0 = t[sc + 0][dh], e1 = t[sc + 1][dh], e2 = t[sc + 2][dh], e3 = t[sc + 3][dh];
    u16 e4 = t[sc + 4][dh], e5 = t[sc + 5][dh], e6 = t[sc + 6][dh], e7 = t[sc + 7][dh];
    uint4 o;
    o.x = (u32)e0 | ((u32)e1 << 16);
    o.y = (u32)e2 | ((u32)e3 << 16);
    o.z = (u32)e4 | ((u32)e5 << 16);
    o.w = (u32)e6 | ((u32)e7 << 16);
    *(uint4*)(Vt + ((size_t)hh * DH_ + dh) * S_ + s0 + sc) = o;
  }
}

// ======== MFMA flash attention v2 (unchanged from round 5) ========
__global__ __launch_bounds__(256) void k_attn2(const u16* __restrict__ qkvb,
                                               const u16* __restrict__ Vt,
                                               u16* __restrict__ out) {
  __shared__ u16 Ks[2][64 * 128];
  __shared__ u16 VTs[2][128 * 64];
  __shared__ u16 PT[4][64 * 16];
  const int tid = threadIdx.x;
  const int lane = tid & 63, w = tid >> 6;
  const int g = lane >> 4, l4 = lane & 15;
  const int p = blockIdx.x;
  const int hh = blockIdx.y;
  const int ld = 6144;
  const float rs = 0.08838834764831845f;
  const int qa0 = p * 64, qb0 = (31 - p) * 64;
  const int ntb = 32 - p;
  char* pt_w = (char*)&PT[w][0];

  const int qga = qa0 + w * 16 + l4;
  const int qgb = qb0 + w * 16 + l4;

  bf16x8 qfa[4], qfb[4];
#pragma unroll
  for (int kh = 0; kh < 4; ++kh) {
    qfa[kh] = *(const bf16x8*)(qkvb + (size_t)qga * ld + hh * DH_ + kh * 32 + g * 8);
    qfb[kh] = *(const bf16x8*)(qkvb + (size_t)qgb * ld + hh * DH_ + kh * 32 + g * 8);
  }

  float ma = -3.0e38f, la = 0.f, mb = -3.0e38f, lb = 0.f;
  f32x4 acc_a[8] = {}, acc_b[8] = {};
  bf16x8 pba[2], pbb[2];

  auto stage = [&](int buf, int kt) {
    const int kv0 = kt * 64;
#pragma unroll
    for (int i = 0; i < 4; ++i) {
      int rl = (w * 4 + i) * 4 + (lane >> 4);
      int cs = (lane & 15) ^ ((rl & 7) ^ (((rl >> 3) & 3) << 1));
      __builtin_amdgcn_global_load_lds(
          (const __attribute__((address_space(1))) void*)(
              qkvb + (size_t)(kv0 + rl) * ld + 2048 + hh * DH_ + cs * 8),
          (__attribute__((address_space(3))) void*)(&Ks[buf][(w * 4 + i) * 512]), 16, 0, 0);
    }
#pragma unroll
    for (int i = 0; i < 4; ++i) {
      int dh = (w * 4 + i) * 8 + (lane >> 3);
      int cs = (lane & 7) ^ (dh & 7);
      __builtin_amdgcn_global_load_lds(
          (const __attribute__((address_space(1))) void*)(
              Vt + ((size_t)hh * DH_ + dh) * S_ + kv0 + cs * 8),
          (__attribute__((address_space(3))) void*)(&VTs[buf][(w * 4 + i) * 512]), 16, 0, 0);
    }
  };

  auto softpb = [&](f32x4* sv, float& m, float& l, f32x4* acc, int qg, bool diag,
                    int kv0, bf16x8* pb) {
    float pv[16];
    float tmax = -3.0e38f;
#pragma unroll
    for (int kb = 0; kb < 4; ++kb)
#pragma unroll
      for (int r = 0; r < 4; ++r) {
        float s = sv[kb][r] * rs;
        if (diag) {
          int kglob = kv0 + kb * 16 + g * 4 + r;
          if (kglob > qg) s = -1.0e30f;
        }
        pv[kb * 4 + r] = s;
        tmax = fmaxf(tmax, s);
      }
    tmax = fmaxf(tmax, __shfl_xor(tmax, 16, 64));
    tmax = fmaxf(tmax, __shfl_xor(tmax, 32, 64));
    float mn = fmaxf(m, tmax);
    float corr = __expf(m - mn);
    m = mn;
    float ps = 0.f;
#pragma unroll
    for (int i = 0; i < 16; ++i) { pv[i] = __expf(pv[i] - mn); ps += pv[i]; }
    ps += __shfl_xor(ps, 16, 64);
    ps += __shfl_xor(ps, 32, 64);
    l = l * corr + ps;
#pragma unroll
    for (int f = 0; f < 8; ++f) {
      acc[f][0] *= corr; acc[f][1] *= corr; acc[f][2] *= corr; acc[f][3] *= corr;
    }
#pragma unroll
    for (int kb = 0; kb < 4; ++kb)
#pragma unroll
      for (int r = 0; r < 4; ++r) {
        int key = kb * 16 + g * 4 + r;
        int byte = (key * 32 + l4 * 2) ^ (((key >> 3) & 3) << 5);
        *(u16*)(pt_w + byte) = f2bf(pv[kb * 4 + r]);
      }
#pragma unroll
    for (int ks = 0; ks < 2; ++ks) {
      union { bf16x8 v; u16 s[8]; } ub;
#pragma unroll
      for (int j = 0; j < 8; ++j) {
        int key = ks * 32 + g * 8 + j;
        int byte = (key * 32 + l4 * 2) ^ (((key >> 3) & 3) << 5);
        ub.s[j] = *(const u16*)(pt_w + byte);
      }
      pb[ks] = ub.v;
    }
  };

  stage(0, 0);
  asm volatile("s_waitcnt vmcnt(0)" ::: "memory");
  __syncthreads();

  for (int kt = 0; kt < ntb; ++kt) {
    const int kv0 = kt * 64;
    const int buf = kt & 1;
    if (kt + 1 < ntb) stage(buf ^ 1, kt + 1);

    const char* kb_base = (const char*)&Ks[buf][0];
    const char* vb_base = (const char*)&VTs[buf][0];
    const bool doa = (kt <= p);

    f32x4 sa[4] = {}, sb[4] = {};
#pragma unroll
    for (int kb = 0; kb < 4; ++kb) {
#pragma unroll
      for (int kh = 0; kh < 4; ++kh) {
        int key = kb * 16 + l4;
        int ch = (kh * 4 + g) ^ ((key & 7) ^ (((key >> 3) & 3) << 1));
        bf16x8 af = *(const bf16x8*)(kb_base + key * 256 + ch * 16);
        if (doa) sa[kb] = MFMA16(af, qfa[kh], sa[kb]);
        sb[kb] = MFMA16(af, qfb[kh], sb[kb]);
      }
    }

    if (doa) softpb(sa, ma, la, acc_a, qga, kt == p, kv0, pba);
    softpb(sb, mb, lb, acc_b, qgb, kt == ntb - 1, kv0, pbb);

#pragma unroll
    for (int f = 0; f < 8; ++f) {
#pragma unroll
      for (int ks = 0; ks < 2; ++ks) {
        int dh = f * 16 + l4;
        int ch = (ks * 4 + g) ^ (dh & 7);
        bf16x8 va = *(const bf16x8*)(vb_base + dh * 128 + ch * 16);
        if (doa) acc_a[f] = MFMA16(va, pba[ks], acc_a[f]);
        acc_b[f] = MFMA16(va, pbb[ks], acc_b[f]);
      }
    }

    if (kt + 1 < ntb) {
      asm volatile("s_waitcnt vmcnt(0)" ::: "memory");
      __syncthreads();
    }
  }

  float inva = 1.f / la, invb = 1.f / lb;
  u16* opa = out + (size_t)qga * D_ + hh * DH_;
  u16* opb = out + (size_t)qgb * D_ + hh * DH_;
#pragma unroll
  for (int f = 0; f < 8; ++f)
#pragma unroll
    for (int r = 0; r < 4; ++r) {
      opa[f * 16 + g * 4 + r] = f2bf(acc_a[f][r] * inva);
      opb[f * 16 + g * 4 + r] = f2bf(acc_b[f][r] * invb);
    }
}

// ---------------- silu(gate)*up ----------------
__global__ __launch_bounds__(256) void k_silumul(u16* __restrict__ gu) {
  size_t i = ((size_t)blockIdx.x * 256 + threadIdx.x) * 4;
  int s = (int)(i >> 13);
  int f = (int)(i & 8191);
  u16* gp = gu + (size_t)s * (2 * DFF_) + f;
  ushort4 gt = *(ushort4*)gp;
  ushort4 up = *(ushort4*)(gp + DFF_);
  float g0 = bf2f(gt.x), g1 = bf2f(gt.y), g2 = bf2f(gt.z), g3 = bf2f(gt.w);
  float u0 = bf2f(up.x), u1 = bf2f(up.y), u2 = bf2f(up.z), u3 = bf2f(up.w);
  ushort4 o;
  o.x = f2bf(g0 / (1.f + __expf(-g0)) * u0);
  o.y = f2bf(g1 / (1.f + __expf(-g1)) * u1);
  o.z = f2bf(g2 / (1.f + __expf(-g2)) * u2);
  o.w = f2bf(g3 / (1.f + __expf(-g3)) * u3);
  *(ushort4*)gp = o;
}

// ---------------- gumbel softmax -> g (bf16) ----------------
__global__ __launch_bounds__(256) void k_gumbel(const float* __restrict__ logits,
                                                const float* __restrict__ u,
                                                u16* __restrict__ g) {
  int s = blockIdx.x;
  const float* lp = logits + (size_t)s * V_;
  const float* up = u + (size_t)s * V_;
  float m = -3.0e38f, l = 0.f;
  for (int v = threadIdx.x; v < V_; v += 256) {
    float z = lp[v] - __logf(-__logf(up[v] + 1e-10f) + 1e-10f);
    float mn = fmaxf(m, z);
    l = l * __expf(m - mn) + __expf(z - mn);
    m = mn;
  }
#pragma unroll
  for (int msk = 1; msk < 64; msk <<= 1) {
    float m2 = __shfl_xor(m, msk, 64), l2 = __shfl_xor(l, msk, 64);
    float mn = fmaxf(m, m2);
    l = l * __expf(m - mn) + l2 * __expf(m2 - mn);
    m = mn;
  }
  __shared__ float shm[4], shl[4];
  if ((threadIdx.x & 63) == 0) { shm[threadIdx.x >> 6] = m; shl[threadIdx.x >> 6] = l; }
  __syncthreads();
  float M = fmaxf(fmaxf(shm[0], shm[1]), fmaxf(shm[2], shm[3]));
  float L = shl[0] * __expf(shm[0] - M) + shl[1] * __expf(shm[1] - M) +
            shl[2] * __expf(shm[2] - M) + shl[3] * __expf(shm[3] - M);
  float inv = 1.f / L;
  u16* gp = g + (size_t)s * V_;
  for (int v = threadIdx.x; v < V_; v += 256) {
    float z = lp[v] - __logf(-__logf(up[v] + 1e-10f) + 1e-10f);
    gp[v] = f2bf(__expf(z - M) * inv);
  }
}

extern "C" void kernel_launch(void* const* d_in, const int* in_sizes, int n_in,
                              void* d_out, int out_size, void* d_ws, size_t ws_size,
                              hipStream_t stream) {
  const int*   ids        = (const int*)d_in[0];
  const float* u          = (const float*)d_in[1];
  const float* emb        = (const float*)d_in[2];
  const float* attn_scale = (const float*)d_in[3];
  const float* gu_scale   = (const float*)d_in[4];
  const float* dn_scale   = (const float*)d_in[5];
  const float* lora_A     = (const float*)d_in[6];
  const float* lora_B     = (const float*)d_in[7];
  const float* norm_w     = (const float*)d_in[8];
  const float* fnorm_w    = (const float*)d_in[9];
  const int*   attn_idx   = (const int*)d_in[10];
  const int*   gu_idx     = (const int*)d_in[11];
  const int*   dn_idx     = (const int*)d_in[12];

  float* out_se = (float*)d_out;
  float* out_lg = (float*)d_out + (size_t)S_ * D_;

  char* W = (char*)d_ws;
  float* h    = (float*)(W);                          // 16 MiB
  u16*   xb   = (u16*)(W + ((size_t)16 << 20));       // 8 MiB
  float* qkv  = (float*)(W + ((size_t)24 << 20));     // 48 MiB
  u16*   qkvb = (u16*)(W + ((size_t)72 << 20));       // 24 MiB
  u16*   Vtb  = (u16*)(W + ((size_t)96 << 20));       // 8 MiB
  u16*   ob   = (u16*)(W + ((size_t)104 << 20));      // 8 MiB
  u16*   gub  = (u16*)(W + ((size_t)112 << 20));      // 64 MiB
  u16*   wdq  = (u16*)(W + ((size_t)176 << 20));      // 64 MiB
  float* Tl   = (float*)(W + ((size_t)240 << 20));    // 192 KiB
  u16*   embb = (u16*)(W);                            // 125 MiB (head)
  u16*   gsm  = (u16*)(W + ((size_t)125 << 20));      // 125 MiB (head)
  u16*   embT = (u16*)(W);                            // 125 MiB (replaces embb)
  u16*   xbh  = (u16*)d_out;                          // final-norm out, parked in out_se
  float* Pk   = (float*)(W + ((size_t)250 << 20));    // 64 MiB split-K partials
  const bool big = ws_size >= ((size_t)314 << 20);
  const size_t ZS = (size_t)4 * 1024 * 1024;

  dim3 b256(256), b512(512);

  k_gather<<<dim3(S_ * D_ / 256), b256, 0, stream>>>(ids, emb, h);

  for (int l = 0; l < L_; ++l) {
    const int*   aidx = attn_idx + (size_t)l * 4 * D_ * D_;
    const float* ascl = attn_scale + (size_t)l * 4 * D_ * (D_ / 64);
    const float* lA   = lora_A + (size_t)l * 4 * R_ * D_;
    const float* lB   = lora_B + (size_t)l * 4 * D_ * R_;

    // ---- attention ----
    k_rmsnorm<<<dim3(S_), b256, 0, stream>>>(h, norm_w + (size_t)l * 2 * D_, xb);
    k_dequant<<<dim3(4 * D_ * D_ / 8 / 256), b256, 0, stream>>>(aidx, ascl, wdq, 11);
    k_gemm256<OUT_F32><<<dim3(3 * D_ / 256, 8), b512, 0, stream>>>(
        xb, D_, wdq, D_, qkv, 3 * D_, D_, 0);
    k_lora_down<<<dim3(S_), b256, 0, stream>>>(xb, lA, Tl, 3);
    k_lora_up_qkv<<<dim3(S_ * 3 * D_ / 4 / 256), b256, 0, stream>>>(qkv, Tl, lB, qkvb);
    k_vtrans<<<dim3(S_ / 64, H_), b256, 0, stream>>>(qkvb, Vtb);
    k_attn2<<<dim3(16, H_), b256, 0, stream>>>(qkvb, Vtb, ob);
    k_gemm256<OUT_F32_ACC><<<dim3(D_ / 256, 8), b512, 0, stream>>>(
        ob, D_, wdq + (size_t)3 * D_ * D_, D_, h, D_, D_, 0);
    k_lora_down<<<dim3(S_), b256, 0, stream>>>(ob, lA + (size_t)3 * R_ * D_, Tl, 1);
    k_lora_up<<<dim3(S_ * D_ / 256), b256, 0, stream>>>(h, D_, Tl, lB + (size_t)3 * D_ * R_, 1);

    // ---- ffn ----
    k_rmsnorm<<<dim3(S_), b256, 0, stream>>>(h, norm_w + (size_t)l * 2 * D_ + D_, xb);
    k_dequant<<<dim3(2 * DFF_ * D_ / 8 / 256), b256, 0, stream>>>(
        gu_idx + (size_t)l * 2 * DFF_ * D_, gu_scale + (size_t)l * 2 * DFF_ * (D_ / 64), wdq, 11);
    k_gemm256<OUT_BF16><<<dim3(2 * DFF_ / 256, 8), b512, 0, stream>>>(
        xb, D_, wdq, D_, gub, 2 * DFF_, D_, 0);
    k_silumul<<<dim3(S_ * DFF_ / 4 / 256), b256, 0, stream>>>(gub);
    k_dequant<<<dim3(D_ * DFF_ / 8 / 256), b256, 0, stream>>>(
        dn_idx + (size_t)l * D_ * DFF_, dn_scale + (size_t)l * D_ * (DFF_ / 64), wdq, 13);
    if (big) {
      k_gemm256<OUT_F32><<<dim3(D_ / 256, 8, 4), b512, 0, stream>>>(
          gub, 2 * DFF_, wdq, DFF_, Pk, D_, DFF_ / 4, ZS);
      k_red<<<dim3(4096), b256, 0, stream>>>(Pk, h, 1);
    } else {
      k_gemm256<OUT_F32_ACC><<<dim3(D_ / 256, 8), b512, 0, stream>>>(
          gub, 2 * DFF_, wdq, DFF_, h, D_, DFF_, 0);
    }
  }

  // ---- head ----
  k_rmsnorm<<<dim3(S_), b256, 0, stream>>>(h, fnorm_w, xbh);
  k_f2b<<<dim3(V_ * D_ / 8 / 256), b256, 0, stream>>>(emb, embb);
  k_gemm256<OUT_F32><<<dim3(V_ / 256, 8), b512, 0, stream>>>(
      xbh, D_, embb, D_, out_lg, V_, D_, 0);
  k_gumbel<<<dim3(S_), b256, 0, stream>>>(out_lg, u, gsm);
  k_transpose<<<dim3(V_ / 64, D_ / 64), b256, 0, stream>>>(emb, embT);
  if (big) {
    k_gemm256<OUT_F32><<<dim3(D_ / 256, 8, 4), b512, 0, stream>>>(
        gsm, V_, embT, V_, Pk, D_, V_ / 4, ZS);
    k_red<<<dim3(4096), b256, 0, stream>>>(Pk, out_se, 0);
  } else {
    k_gemm256<OUT_F32><<<dim3(D_ / 256, 8), b512, 0, stream>>>(
        gsm, V_, embT, V_, out_se, D_, V_, 0);
  }
}